// Round 3
// baseline (1052.574 us; speedup 1.0000x reference)
//
#include <hip/hip_runtime.h>
#include <math.h>

// Transformer-XL relative multi-head attention, fp32, MI355X.
// B=2, S=2048, D=512, H=8, dh=64.
//
// Pipeline:
//  1. proj_kernel   : x@Wq(+bq)->QU/QV (u/v folded), x@Wk->KT (transposed),
//                     x@Wv->V, pos@Wp->PT (transposed).  One launch, mode=blockIdx.z.
//  2. per head-chunk (sized by ws_size):
//     a. score_gemm<false> : content = QU_h @ KT_h   -> scores[z][2048][2048]
//     b. score_gemm<true>  : Ppos = QV_h @ PT_h, epilogue scatter-adds through the
//        rel_shift mapping into the content buffer (bijection -> race-free +=):
//          score[q][k] += Ppos[q, k+S-1-q]   (k<=q)
//          score[q][k] += Ppos[q+1, k-q-2]   (k>=q+2);  k=q+1 stays content-only (pad=0)
//     c. softmax_kernel : row softmax of score/sqrt(512), in place
//     d. pv_gemm : ctx_part[kz] = attn @ V_h  (split-K=2, two partial ctx buffers)
//  3. out_gemm : out = (ctx_a+ctx_b) @ Wo + bo
//
// All GEMMs: 256 threads, 8x8 register micro-tiles, K-chunks of 32 staged in LDS
// (A transposed in LDS so micro reads are float4; A-reads are wave-broadcast).
//
// Hardening: if ws_size is too small for the pipeline (needs ~75.5 MB), zero-fill
// d_out and return — never write beyond d_ws.

#define S_LEN 2048
#define NB 2
#define NH 8
#define DHD 64
#define DM 512
#define NBH 16

#define HEAD_ELEMS (S_LEN * DHD)            // 131072 floats per head tensor
#define TEN_ELEMS  (NBH * HEAD_ELEMS)       // 2097152 floats per [B,H,S,dh] tensor
#define OFF_QU 0
#define OFF_QV (OFF_QU + TEN_ELEMS)
#define OFF_KT (OFF_QV + TEN_ELEMS)
#define OFF_PT (OFF_KT + TEN_ELEMS)
#define OFF_V  (OFF_PT + TEN_ELEMS)
#define OFF_CTXA (OFF_V + TEN_ELEMS)
#define OFF_CTXB (OFF_CTXA + TEN_ELEMS)
#define OFF_SC (OFF_CTXB + TEN_ELEMS)       // 14,680,064 floats fixed (58.7 MB)
#define SS ((size_t)S_LEN * (size_t)S_LEN)  // 4,194,304 floats per head score mat

// ---------------------------------------------------------------------------
// Projections: C[4096,512] = A[4096,512] @ W[512,512] (+bias), mode-specific store.
// mode 0: q -> QU=q+bq+u, QV=q+bq+v   [bh][s][d]
// mode 1: k -> KT = (x@Wk+bk)^T       [bh][d][s]
// mode 2: v -> V                      [bh][s][d]
// mode 3: p -> PT = (pos@Wp)^T        [bh][d][s]   (no bias)
// ---------------------------------------------------------------------------
__global__ __launch_bounds__(256)
void proj_kernel(const float* __restrict__ x, const float* __restrict__ pos,
                 const float* __restrict__ Wq, const float* __restrict__ bq,
                 const float* __restrict__ Wk, const float* __restrict__ bk,
                 const float* __restrict__ Wv, const float* __restrict__ bvp,
                 const float* __restrict__ Wp,
                 const float* __restrict__ uvec, const float* __restrict__ vvec,
                 float* __restrict__ ws)
{
    __shared__ float Ast[32][132];   // A chunk, transposed [kc][m]
    __shared__ float Bs[32][132];    // W chunk [kc][n]
    const int t = threadIdx.x;
    const int tx = t & 15, ty = t >> 4;      // tx: n-dir (8 cols), ty: m-dir (8 rows)
    const int mode = blockIdx.z;
    const int n0 = blockIdx.x * 128, m0 = blockIdx.y * 128;

    const float* A = (mode == 3) ? pos : x;
    const float* W = (mode == 0) ? Wq : (mode == 1) ? Wk : (mode == 2) ? Wv : Wp;

    float acc[8][8];
#pragma unroll
    for (int i = 0; i < 8; ++i)
#pragma unroll
        for (int j = 0; j < 8; ++j) acc[i][j] = 0.f;

    for (int k0 = 0; k0 < 512; k0 += 32) {
#pragma unroll
        for (int i = 0; i < 4; ++i) {        // A tile 128x32, transpose into LDS
            int f = t + i * 256;
            int row = f >> 3, kq = f & 7;
            float4 a4 = *(const float4*)(A + (size_t)(m0 + row) * 512 + k0 + kq * 4);
            Ast[kq * 4 + 0][row] = a4.x; Ast[kq * 4 + 1][row] = a4.y;
            Ast[kq * 4 + 2][row] = a4.z; Ast[kq * 4 + 3][row] = a4.w;
        }
#pragma unroll
        for (int i = 0; i < 4; ++i) {        // W tile 32x128
            int f = t + i * 256;
            int row = f >> 5, c4 = f & 31;
            *(float4*)&Bs[row][c4 * 4] =
                *(const float4*)(W + (size_t)(k0 + row) * 512 + n0 + c4 * 4);
        }
        __syncthreads();
#pragma unroll
        for (int kc = 0; kc < 32; ++kc) {
            float a[8], b[8];
            *(float4*)&a[0] = *(const float4*)&Ast[kc][ty * 8];
            *(float4*)&a[4] = *(const float4*)&Ast[kc][ty * 8 + 4];
            *(float4*)&b[0] = *(const float4*)&Bs[kc][tx * 8];
            *(float4*)&b[4] = *(const float4*)&Bs[kc][tx * 8 + 4];
#pragma unroll
            for (int i = 0; i < 8; ++i)
#pragma unroll
                for (int j = 0; j < 8; ++j) acc[i][j] = fmaf(a[i], b[j], acc[i][j]);
        }
        __syncthreads();
    }

    const int bb = m0 >> 11;   // batch index (tile never crosses the 2048 boundary)

    if (mode == 0) {
        float* qu = ws + OFF_QU; float* qv = ws + OFF_QV;
#pragma unroll
        for (int i = 0; i < 8; ++i) {
            int gm = m0 + ty * 8 + i, srow = gm & 2047;
#pragma unroll
            for (int j4 = 0; j4 < 2; ++j4) {
                int gn = n0 + tx * 8 + j4 * 4;
                int h = gn >> 6, d = gn & 63;
                float4 bi = *(const float4*)(bq + gn);
                float4 uu = *(const float4*)(uvec + gn);   // u index == gn (h*64+d)
                float4 vv = *(const float4*)(vvec + gn);
                float c0 = acc[i][j4 * 4 + 0] + bi.x, c1 = acc[i][j4 * 4 + 1] + bi.y;
                float c2 = acc[i][j4 * 4 + 2] + bi.z, c3 = acc[i][j4 * 4 + 3] + bi.w;
                size_t o = ((size_t)(bb * NH + h) * S_LEN + srow) * DHD + d;
                *(float4*)(qu + o) = make_float4(c0 + uu.x, c1 + uu.y, c2 + uu.z, c3 + uu.w);
                *(float4*)(qv + o) = make_float4(c0 + vv.x, c1 + vv.y, c2 + vv.z, c3 + vv.w);
            }
        }
    } else if (mode == 1 || mode == 3) {
        float* dst = ws + (mode == 1 ? OFF_KT : OFF_PT);
        const float* bias = (mode == 1) ? bk : nullptr;
#pragma unroll
        for (int j = 0; j < 8; ++j) {
            int gn = n0 + tx * 8 + j;
            int h = gn >> 6, d = gn & 63;
            float bval = bias ? bias[gn] : 0.f;
            size_t rowbase = ((size_t)(bb * NH + h) * DHD + d) * S_LEN;
#pragma unroll
            for (int i4 = 0; i4 < 2; ++i4) {
                int srow = (m0 & 2047) + ty * 8 + i4 * 4;
                float4 o4 = make_float4(acc[i4 * 4 + 0][j] + bval, acc[i4 * 4 + 1][j] + bval,
                                        acc[i4 * 4 + 2][j] + bval, acc[i4 * 4 + 3][j] + bval);
                *(float4*)(dst + rowbase + srow) = o4;
            }
        }
    } else {   // mode 2: V
        float* dst = ws + OFF_V;
#pragma unroll
        for (int i = 0; i < 8; ++i) {
            int gm = m0 + ty * 8 + i, srow = gm & 2047;
#pragma unroll
            for (int j4 = 0; j4 < 2; ++j4) {
                int gn = n0 + tx * 8 + j4 * 4;
                int h = gn >> 6, d = gn & 63;
                float4 bi = *(const float4*)(bvp + gn);
                size_t o = ((size_t)(bb * NH + h) * S_LEN + srow) * DHD + d;
                *(float4*)(dst + o) = make_float4(acc[i][j4 * 4 + 0] + bi.x,
                                                  acc[i][j4 * 4 + 1] + bi.y,
                                                  acc[i][j4 * 4 + 2] + bi.z,
                                                  acc[i][j4 * 4 + 3] + bi.w);
            }
        }
    }
}

// ---------------------------------------------------------------------------
// Score GEMM: C[2048,2048] = A_h[2048,64] @ Bt_h[64,2048].
// SCATTER=false : plain store (content scores).
// SCATTER=true  : rel_shift scatter-add into existing score buffer.
// ---------------------------------------------------------------------------
template<bool SCATTER>
__global__ __launch_bounds__(256)
void score_gemm(const float* __restrict__ Aq, const float* __restrict__ Bt,
                float* __restrict__ sc, int head_base)
{
    __shared__ float Ast[32][132];
    __shared__ float Bs[32][132];
    const int t = threadIdx.x;
    const int tx = t & 15, ty = t >> 4;
    const int n0 = blockIdx.x * 128, m0 = blockIdx.y * 128, z = blockIdx.z;
    const int g = head_base + z;
    const float* A  = Aq + (size_t)g * HEAD_ELEMS;   // [2048][64]
    const float* Bb = Bt + (size_t)g * HEAD_ELEMS;   // [64][2048]
    float* out = sc + (size_t)z * SS;

    float acc[8][8];
#pragma unroll
    for (int i = 0; i < 8; ++i)
#pragma unroll
        for (int j = 0; j < 8; ++j) acc[i][j] = 0.f;

    for (int k0 = 0; k0 < 64; k0 += 32) {
#pragma unroll
        for (int i = 0; i < 4; ++i) {
            int f = t + i * 256;
            int row = f >> 3, kq = f & 7;
            float4 a4 = *(const float4*)(A + (size_t)(m0 + row) * DHD + k0 + kq * 4);
            Ast[kq * 4 + 0][row] = a4.x; Ast[kq * 4 + 1][row] = a4.y;
            Ast[kq * 4 + 2][row] = a4.z; Ast[kq * 4 + 3][row] = a4.w;
        }
#pragma unroll
        for (int i = 0; i < 4; ++i) {
            int f = t + i * 256;
            int row = f >> 5, c4 = f & 31;
            *(float4*)&Bs[row][c4 * 4] =
                *(const float4*)(Bb + (size_t)(k0 + row) * S_LEN + n0 + c4 * 4);
        }
        __syncthreads();
#pragma unroll
        for (int kc = 0; kc < 32; ++kc) {
            float a[8], b[8];
            *(float4*)&a[0] = *(const float4*)&Ast[kc][ty * 8];
            *(float4*)&a[4] = *(const float4*)&Ast[kc][ty * 8 + 4];
            *(float4*)&b[0] = *(const float4*)&Bs[kc][tx * 8];
            *(float4*)&b[4] = *(const float4*)&Bs[kc][tx * 8 + 4];
#pragma unroll
            for (int i = 0; i < 8; ++i)
#pragma unroll
                for (int j = 0; j < 8; ++j) acc[i][j] = fmaf(a[i], b[j], acc[i][j]);
        }
        __syncthreads();
    }

    if (!SCATTER) {
#pragma unroll
        for (int i = 0; i < 8; ++i) {
            int gm = m0 + ty * 8 + i;
#pragma unroll
            for (int j4 = 0; j4 < 2; ++j4) {
                int gn = n0 + tx * 8 + j4 * 4;
                *(float4*)(out + (size_t)gm * S_LEN + gn) =
                    make_float4(acc[i][j4 * 4 + 0], acc[i][j4 * 4 + 1],
                                acc[i][j4 * 4 + 2], acc[i][j4 * 4 + 3]);
            }
        }
    } else {
        // Ppos[q][j] -> score[q][j+q-(S-1)] if j >= S-1-q, else score[q-1][j+q+1].
        // Bijective over targets -> non-atomic += is race-free across blocks.
#pragma unroll
        for (int i = 0; i < 8; ++i) {
            int q = m0 + ty * 8 + i;
            int thresh = S_LEN - 1 - q;
#pragma unroll
            for (int j = 0; j < 8; ++j) {
                int jg = n0 + tx * 8 + j;
                float val = acc[i][j];
                if (jg >= thresh) {
                    out[(size_t)q * S_LEN + (jg + q - (S_LEN - 1))] += val;
                } else if (q > 0) {
                    out[(size_t)(q - 1) * S_LEN + (jg + q + 1)] += val;
                }
            }
        }
    }
}

// ---------------------------------------------------------------------------
// Row softmax of score/sqrt(512), in place.  One block (256 thr) per row.
// ---------------------------------------------------------------------------
__global__ __launch_bounds__(256)
void softmax_kernel(float* __restrict__ sc)
{
    const int q = blockIdx.x, z = blockIdx.y;
    float* row = sc + (size_t)z * SS + (size_t)q * S_LEN;
    const int t = threadIdx.x;
    const float scale = 0.04419417382415922f;   // 1/sqrt(512)

    float v[8];
#pragma unroll
    for (int i = 0; i < 8; ++i) v[i] = row[t + i * 256] * scale;

    float mx = v[0];
#pragma unroll
    for (int i = 1; i < 8; ++i) mx = fmaxf(mx, v[i]);
#pragma unroll
    for (int o = 32; o; o >>= 1) mx = fmaxf(mx, __shfl_xor(mx, o));

    __shared__ float r1[4], r2[4];
    const int w = t >> 6, lane = t & 63;
    if (!lane) r1[w] = mx;
    __syncthreads();
    mx = fmaxf(fmaxf(r1[0], r1[1]), fmaxf(r1[2], r1[3]));

    float e[8], sum = 0.f;
#pragma unroll
    for (int i = 0; i < 8; ++i) { e[i] = __expf(v[i] - mx); sum += e[i]; }
#pragma unroll
    for (int o = 32; o; o >>= 1) sum += __shfl_xor(sum, o);
    if (!lane) r2[w] = sum;
    __syncthreads();
    sum = r2[0] + r2[1] + r2[2] + r2[3];

    float inv = 1.f / sum;
#pragma unroll
    for (int i = 0; i < 8; ++i) row[t + i * 256] = e[i] * inv;
}

// ---------------------------------------------------------------------------
// PV GEMM: ctx_part = attn[2048,2048] @ V_h[2048,64], split-K=2 (blockIdx.y),
// tile [256 q x 64 d], 8x8 micro.  Store into ctx[b][s][h*64+d] partial buffers.
// ---------------------------------------------------------------------------
__global__ __launch_bounds__(256)
void pv_gemm(const float* __restrict__ sc, const float* __restrict__ vbuf,
             float* __restrict__ ca, float* __restrict__ cb, int head_base)
{
    __shared__ float Ast[32][260];
    __shared__ float Bs2[32][68];
    const int t = threadIdx.x;
    const int tx = t & 7, ty = t >> 3;       // tx: d (8 cols), ty: q (8 rows of 32)
    const int qt = blockIdx.x, kz = blockIdx.y, z = blockIdx.z;
    const int g = head_base + z;
    const float* A = sc + (size_t)z * SS + (size_t)qt * 256 * S_LEN + (size_t)kz * 1024;
    const float* V = vbuf + (size_t)g * HEAD_ELEMS + (size_t)kz * 1024 * DHD;

    float acc[8][8];
#pragma unroll
    for (int i = 0; i < 8; ++i)
#pragma unroll
        for (int j = 0; j < 8; ++j) acc[i][j] = 0.f;

    for (int k0 = 0; k0 < 1024; k0 += 32) {
#pragma unroll
        for (int i = 0; i < 8; ++i) {        // attn tile 256x32, transpose
            int f = t + i * 256;
            int row = f >> 3, kq = f & 7;
            float4 a4 = *(const float4*)(A + (size_t)row * S_LEN + k0 + kq * 4);
            Ast[kq * 4 + 0][row] = a4.x; Ast[kq * 4 + 1][row] = a4.y;
            Ast[kq * 4 + 2][row] = a4.z; Ast[kq * 4 + 3][row] = a4.w;
        }
#pragma unroll
        for (int i = 0; i < 2; ++i) {        // V tile 32x64
            int f = t + i * 256;
            int row = f >> 4, c4 = f & 15;
            *(float4*)&Bs2[row][c4 * 4] =
                *(const float4*)(V + (size_t)(k0 + row) * DHD + c4 * 4);
        }
        __syncthreads();
#pragma unroll
        for (int kc = 0; kc < 32; ++kc) {
            float a[8], b[8];
            *(float4*)&a[0] = *(const float4*)&Ast[kc][ty * 8];
            *(float4*)&a[4] = *(const float4*)&Ast[kc][ty * 8 + 4];
            *(float4*)&b[0] = *(const float4*)&Bs2[kc][tx * 8];
            *(float4*)&b[4] = *(const float4*)&Bs2[kc][tx * 8 + 4];
#pragma unroll
            for (int i = 0; i < 8; ++i)
#pragma unroll
                for (int j = 0; j < 8; ++j) acc[i][j] = fmaf(a[i], b[j], acc[i][j]);
        }
        __syncthreads();
    }

    float* ctx = kz ? cb : ca;
    const int bb = g >> 3, h = g & 7;
#pragma unroll
    for (int i = 0; i < 8; ++i) {
        int q = qt * 256 + ty * 8 + i;
        size_t o = ((size_t)(bb * S_LEN + q)) * DM + h * DHD + tx * 8;
        *(float4*)(ctx + o)     = make_float4(acc[i][0], acc[i][1], acc[i][2], acc[i][3]);
        *(float4*)(ctx + o + 4) = make_float4(acc[i][4], acc[i][5], acc[i][6], acc[i][7]);
    }
}

// ---------------------------------------------------------------------------
// Output GEMM: out[4096,512] = (ctx_a+ctx_b)[4096,512] @ Wo + bo
// ---------------------------------------------------------------------------
__global__ __launch_bounds__(256)
void out_gemm(const float* __restrict__ ca, const float* __restrict__ cb,
              const float* __restrict__ Wo, const float* __restrict__ bo,
              float* __restrict__ out)
{
    __shared__ float Ast[32][132];
    __shared__ float Bs[32][132];
    const int t = threadIdx.x;
    const int tx = t & 15, ty = t >> 4;
    const int n0 = blockIdx.x * 128, m0 = blockIdx.y * 128;

    float acc[8][8];
#pragma unroll
    for (int i = 0; i < 8; ++i)
#pragma unroll
        for (int j = 0; j < 8; ++j) acc[i][j] = 0.f;

    for (int k0 = 0; k0 < 512; k0 += 32) {
#pragma unroll
        for (int i = 0; i < 4; ++i) {
            int f = t + i * 256;
            int row = f >> 3, kq = f & 7;
            size_t go = (size_t)(m0 + row) * 512 + k0 + kq * 4;
            float4 a4 = *(const float4*)(ca + go);
            float4 b4 = *(const float4*)(cb + go);
            Ast[kq * 4 + 0][row] = a4.x + b4.x; Ast[kq * 4 + 1][row] = a4.y + b4.y;
            Ast[kq * 4 + 2][row] = a4.z + b4.z; Ast[kq * 4 + 3][row] = a4.w + b4.w;
        }
#pragma unroll
        for (int i = 0; i < 4; ++i) {
            int f = t + i * 256;
            int row = f >> 5, c4 = f & 31;
            *(float4*)&Bs[row][c4 * 4] =
                *(const float4*)(Wo + (size_t)(k0 + row) * 512 + n0 + c4 * 4);
        }
        __syncthreads();
#pragma unroll
        for (int kc = 0; kc < 32; ++kc) {
            float a[8], b[8];
            *(float4*)&a[0] = *(const float4*)&Ast[kc][ty * 8];
            *(float4*)&a[4] = *(const float4*)&Ast[kc][ty * 8 + 4];
            *(float4*)&b[0] = *(const float4*)&Bs[kc][tx * 8];
            *(float4*)&b[4] = *(const float4*)&Bs[kc][tx * 8 + 4];
#pragma unroll
            for (int i = 0; i < 8; ++i)
#pragma unroll
                for (int j = 0; j < 8; ++j) acc[i][j] = fmaf(a[i], b[j], acc[i][j]);
        }
        __syncthreads();
    }

#pragma unroll
    for (int i = 0; i < 8; ++i) {
        int gm = m0 + ty * 8 + i;
#pragma unroll
        for (int j4 = 0; j4 < 2; ++j4) {
            int gn = n0 + tx * 8 + j4 * 4;
            float4 bi = *(const float4*)(bo + gn);
            *(float4*)(out + (size_t)gm * 512 + gn) =
                make_float4(acc[i][j4 * 4 + 0] + bi.x, acc[i][j4 * 4 + 1] + bi.y,
                            acc[i][j4 * 4 + 2] + bi.z, acc[i][j4 * 4 + 3] + bi.w);
        }
    }
}

// Fallback when ws_size is insufficient: write zeros to d_out (wrong answer,
// but no out-of-bounds writes -> clean mismatch report instead of a crash).
__global__ void zero_fill(float* __restrict__ p, int n)
{
    int i = blockIdx.x * 256 + threadIdx.x;
    if (i < n) p[i] = 0.f;
}

// ---------------------------------------------------------------------------
extern "C" void kernel_launch(void* const* d_in, const int* in_sizes, int n_in,
                              void* d_out, int out_size, void* d_ws, size_t ws_size,
                              hipStream_t stream)
{
    const float* x   = (const float*)d_in[0];
    const float* pos = (const float*)d_in[1];
    const float* Wq  = (const float*)d_in[2];
    const float* bq  = (const float*)d_in[3];
    const float* Wk  = (const float*)d_in[4];
    const float* bk  = (const float*)d_in[5];
    const float* Wv  = (const float*)d_in[6];
    const float* bv  = (const float*)d_in[7];
    const float* Wp  = (const float*)d_in[8];
    const float* u   = (const float*)d_in[9];
    const float* v   = (const float*)d_in[10];
    const float* Wo  = (const float*)d_in[11];
    const float* bo  = (const float*)d_in[12];
    float* ws  = (float*)d_ws;
    float* out = (float*)d_out;

    // Workspace guard: need OFF_SC + >=1 head of score buffer.
    const size_t need_bytes = ((size_t)OFF_SC + SS) * sizeof(float);
    if (ws_size < need_bytes) {
        zero_fill<<<(out_size + 255) / 256, 256, 0, stream>>>(out, out_size);
        return;
    }

    // 1. projections (modes 0..3 in one launch via blockIdx.z)
    proj_kernel<<<dim3(4, 32, 4), 256, 0, stream>>>(x, pos, Wq, bq, Wk, bk, Wv, bv,
                                                    Wp, u, v, ws);

    // 2. attention, in head-chunks sized to the workspace
    long ws_floats = (long)(ws_size / 4);
    long avail = ws_floats - (long)OFF_SC;
    int c = (int)(avail / (long)SS);
    if (c < 1) c = 1;
    if (c > NBH) c = NBH;

    for (int g0 = 0; g0 < NBH; g0 += c) {
        int cc = (NBH - g0 < c) ? (NBH - g0) : c;
        score_gemm<false><<<dim3(16, 16, cc), 256, 0, stream>>>(ws + OFF_QU, ws + OFF_KT,
                                                                ws + OFF_SC, g0);
        score_gemm<true><<<dim3(16, 16, cc), 256, 0, stream>>>(ws + OFF_QV, ws + OFF_PT,
                                                               ws + OFF_SC, g0);
        softmax_kernel<<<dim3(S_LEN, cc), 256, 0, stream>>>(ws + OFF_SC);
        pv_gemm<<<dim3(8, 2, cc), 256, 0, stream>>>(ws + OFF_SC, ws + OFF_V,
                                                    ws + OFF_CTXA, ws + OFF_CTXB, g0);
    }

    // 3. output projection
    out_gemm<<<dim3(4, 32, 1), 256, 0, stream>>>(ws + OFF_CTXA, ws + OFF_CTXB, Wo, bo, out);
}

// Round 4
// 957.843 us; speedup vs baseline: 1.0989x; 1.0989x over previous
//
#include <hip/hip_runtime.h>
#include <math.h>

// Transformer-XL relative multi-head attention, fp32, MI355X.
// B=2, S=2048, D=512, H=8, dh=64.
//
// Round-4 structure (flash-style fusion; scores never hit HBM):
//  1. proj_kernel : x@Wq(+bq)->QU/QV (u/v folded), x@Wk->KT (transposed),
//                   x@Wv->V, pos@Wp->PT (transposed). One launch, mode=blockIdx.z.
//  2. per head-chunk:
//     a. pos_gemm  : Ppos = QV_h @ PT_h  -> [S,S] per head (plain aligned write)
//     b. attn_fused: per (head, 128-row q-tile): content = QU@KT tile (LDS GEMM),
//        + gathered rel-shifted Ppos (linear-trick: addr = q*(S-1)+k+S-1, minus 1
//        when k>q, zeroed at k==q+1), online softmax, P@V accumulated in regs
//        (P via swizzled LDS transpose). Writes ctx[b][s][h*64+d] once.
//  3. out_gemm : out = ctx @ Wo + bo

#define S_LEN 2048
#define NB 2
#define NH 8
#define DHD 64
#define DM 512
#define NBH 16

#define HEAD_ELEMS (S_LEN * DHD)            // 131072 floats per head tensor
#define TEN_ELEMS  (NBH * HEAD_ELEMS)       // 2097152 floats per [B,H,S,dh] tensor
#define OFF_QU 0
#define OFF_QV (OFF_QU + TEN_ELEMS)
#define OFF_KT (OFF_QV + TEN_ELEMS)
#define OFF_PT (OFF_KT + TEN_ELEMS)
#define OFF_V  (OFF_PT + TEN_ELEMS)
#define OFF_CTX (OFF_V + TEN_ELEMS)
#define OFF_P  (OFF_CTX + TEN_ELEMS)        // 12,582,912 floats fixed (50.3 MB)
#define SS ((size_t)S_LEN * (size_t)S_LEN)  // 4,194,304 floats per head Ppos mat

// ---------------------------------------------------------------------------
// Projections: C[4096,512] = A[4096,512] @ W[512,512] (+bias), mode-specific store.
// mode 0: q -> QU=q+bq+u, QV=q+bq+v   [bh][s][d]
// mode 1: k -> KT = (x@Wk+bk)^T       [bh][d][s]
// mode 2: v -> V                      [bh][s][d]
// mode 3: p -> PT = (pos@Wp)^T        [bh][d][s]   (no bias)
// ---------------------------------------------------------------------------
__global__ __launch_bounds__(256)
void proj_kernel(const float* __restrict__ x, const float* __restrict__ pos,
                 const float* __restrict__ Wq, const float* __restrict__ bq,
                 const float* __restrict__ Wk, const float* __restrict__ bk,
                 const float* __restrict__ Wv, const float* __restrict__ bvp,
                 const float* __restrict__ Wp,
                 const float* __restrict__ uvec, const float* __restrict__ vvec,
                 float* __restrict__ ws)
{
    __shared__ float Ast[32][132];   // A chunk, transposed [kc][m]
    __shared__ float Bs[32][132];    // W chunk [kc][n]
    const int t = threadIdx.x;
    const int tx = t & 15, ty = t >> 4;
    const int mode = blockIdx.z;
    const int n0 = blockIdx.x * 128, m0 = blockIdx.y * 128;

    const float* A = (mode == 3) ? pos : x;
    const float* W = (mode == 0) ? Wq : (mode == 1) ? Wk : (mode == 2) ? Wv : Wp;

    float acc[8][8];
#pragma unroll
    for (int i = 0; i < 8; ++i)
#pragma unroll
        for (int j = 0; j < 8; ++j) acc[i][j] = 0.f;

    for (int k0 = 0; k0 < 512; k0 += 32) {
#pragma unroll
        for (int i = 0; i < 4; ++i) {
            int f = t + i * 256;
            int row = f >> 3, kq = f & 7;
            float4 a4 = *(const float4*)(A + (size_t)(m0 + row) * 512 + k0 + kq * 4);
            Ast[kq * 4 + 0][row] = a4.x; Ast[kq * 4 + 1][row] = a4.y;
            Ast[kq * 4 + 2][row] = a4.z; Ast[kq * 4 + 3][row] = a4.w;
        }
#pragma unroll
        for (int i = 0; i < 4; ++i) {
            int f = t + i * 256;
            int row = f >> 5, c4 = f & 31;
            *(float4*)&Bs[row][c4 * 4] =
                *(const float4*)(W + (size_t)(k0 + row) * 512 + n0 + c4 * 4);
        }
        __syncthreads();
#pragma unroll
        for (int kc = 0; kc < 32; ++kc) {
            float a[8], b[8];
            *(float4*)&a[0] = *(const float4*)&Ast[kc][ty * 8];
            *(float4*)&a[4] = *(const float4*)&Ast[kc][ty * 8 + 4];
            *(float4*)&b[0] = *(const float4*)&Bs[kc][tx * 8];
            *(float4*)&b[4] = *(const float4*)&Bs[kc][tx * 8 + 4];
#pragma unroll
            for (int i = 0; i < 8; ++i)
#pragma unroll
                for (int j = 0; j < 8; ++j) acc[i][j] = fmaf(a[i], b[j], acc[i][j]);
        }
        __syncthreads();
    }

    const int bb = m0 >> 11;

    if (mode == 0) {
        float* qu = ws + OFF_QU; float* qv = ws + OFF_QV;
#pragma unroll
        for (int i = 0; i < 8; ++i) {
            int gm = m0 + ty * 8 + i, srow = gm & 2047;
#pragma unroll
            for (int j4 = 0; j4 < 2; ++j4) {
                int gn = n0 + tx * 8 + j4 * 4;
                int h = gn >> 6, d = gn & 63;
                float4 bi = *(const float4*)(bq + gn);
                float4 uu = *(const float4*)(uvec + gn);
                float4 vv = *(const float4*)(vvec + gn);
                float c0 = acc[i][j4 * 4 + 0] + bi.x, c1 = acc[i][j4 * 4 + 1] + bi.y;
                float c2 = acc[i][j4 * 4 + 2] + bi.z, c3 = acc[i][j4 * 4 + 3] + bi.w;
                size_t o = ((size_t)(bb * NH + h) * S_LEN + srow) * DHD + d;
                *(float4*)(qu + o) = make_float4(c0 + uu.x, c1 + uu.y, c2 + uu.z, c3 + uu.w);
                *(float4*)(qv + o) = make_float4(c0 + vv.x, c1 + vv.y, c2 + vv.z, c3 + vv.w);
            }
        }
    } else if (mode == 1 || mode == 3) {
        float* dst = ws + (mode == 1 ? OFF_KT : OFF_PT);
        const float* bias = (mode == 1) ? bk : nullptr;
#pragma unroll
        for (int j = 0; j < 8; ++j) {
            int gn = n0 + tx * 8 + j;
            int h = gn >> 6, d = gn & 63;
            float bval = bias ? bias[gn] : 0.f;
            size_t rowbase = ((size_t)(bb * NH + h) * DHD + d) * S_LEN;
#pragma unroll
            for (int i4 = 0; i4 < 2; ++i4) {
                int srow = (m0 & 2047) + ty * 8 + i4 * 4;
                float4 o4 = make_float4(acc[i4 * 4 + 0][j] + bval, acc[i4 * 4 + 1][j] + bval,
                                        acc[i4 * 4 + 2][j] + bval, acc[i4 * 4 + 3][j] + bval);
                *(float4*)(dst + rowbase + srow) = o4;
            }
        }
    } else {   // mode 2: V
        float* dst = ws + OFF_V;
#pragma unroll
        for (int i = 0; i < 8; ++i) {
            int gm = m0 + ty * 8 + i, srow = gm & 2047;
#pragma unroll
            for (int j4 = 0; j4 < 2; ++j4) {
                int gn = n0 + tx * 8 + j4 * 4;
                int h = gn >> 6, d = gn & 63;
                float4 bi = *(const float4*)(bvp + gn);
                size_t o = ((size_t)(bb * NH + h) * S_LEN + srow) * DHD + d;
                *(float4*)(dst + o) = make_float4(acc[i][j4 * 4 + 0] + bi.x,
                                                  acc[i][j4 * 4 + 1] + bi.y,
                                                  acc[i][j4 * 4 + 2] + bi.z,
                                                  acc[i][j4 * 4 + 3] + bi.w);
            }
        }
    }
}

// ---------------------------------------------------------------------------
// pos GEMM: Ppos[z][2048][2048] = QV_h[2048,64] @ PT_h[64,2048]. Plain store.
// ---------------------------------------------------------------------------
__global__ __launch_bounds__(256)
void pos_gemm(const float* __restrict__ Aq, const float* __restrict__ Bt,
              float* __restrict__ pp, int head_base)
{
    __shared__ float Ast[32][132];
    __shared__ float Bs[32][132];
    const int t = threadIdx.x;
    const int tx = t & 15, ty = t >> 4;
    const int n0 = blockIdx.x * 128, m0 = blockIdx.y * 128, z = blockIdx.z;
    const int g = head_base + z;
    const float* A  = Aq + (size_t)g * HEAD_ELEMS;   // [2048][64]
    const float* Bb = Bt + (size_t)g * HEAD_ELEMS;   // [64][2048]
    float* out = pp + (size_t)z * SS;

    float acc[8][8];
#pragma unroll
    for (int i = 0; i < 8; ++i)
#pragma unroll
        for (int j = 0; j < 8; ++j) acc[i][j] = 0.f;

    for (int k0 = 0; k0 < 64; k0 += 32) {
#pragma unroll
        for (int i = 0; i < 4; ++i) {
            int f = t + i * 256;
            int row = f >> 3, kq = f & 7;
            float4 a4 = *(const float4*)(A + (size_t)(m0 + row) * DHD + k0 + kq * 4);
            Ast[kq * 4 + 0][row] = a4.x; Ast[kq * 4 + 1][row] = a4.y;
            Ast[kq * 4 + 2][row] = a4.z; Ast[kq * 4 + 3][row] = a4.w;
        }
#pragma unroll
        for (int i = 0; i < 4; ++i) {
            int f = t + i * 256;
            int row = f >> 5, c4 = f & 31;
            *(float4*)&Bs[row][c4 * 4] =
                *(const float4*)(Bb + (size_t)(k0 + row) * S_LEN + n0 + c4 * 4);
        }
        __syncthreads();
#pragma unroll
        for (int kc = 0; kc < 32; ++kc) {
            float a[8], b[8];
            *(float4*)&a[0] = *(const float4*)&Ast[kc][ty * 8];
            *(float4*)&a[4] = *(const float4*)&Ast[kc][ty * 8 + 4];
            *(float4*)&b[0] = *(const float4*)&Bs[kc][tx * 8];
            *(float4*)&b[4] = *(const float4*)&Bs[kc][tx * 8 + 4];
#pragma unroll
            for (int i = 0; i < 8; ++i)
#pragma unroll
                for (int j = 0; j < 8; ++j) acc[i][j] = fmaf(a[i], b[j], acc[i][j]);
        }
        __syncthreads();
    }

#pragma unroll
    for (int i = 0; i < 8; ++i) {
        int gm = m0 + ty * 8 + i;
#pragma unroll
        for (int j4 = 0; j4 < 2; ++j4) {
            int gn = n0 + tx * 8 + j4 * 4;
            *(float4*)(out + (size_t)gm * S_LEN + gn) =
                make_float4(acc[i][j4 * 4 + 0], acc[i][j4 * 4 + 1],
                            acc[i][j4 * 4 + 2], acc[i][j4 * 4 + 3]);
        }
    }
}

// ---------------------------------------------------------------------------
// Fused attention: per block = (head z, q-tile of 128 rows), 512 threads.
// K-loop over 16 k-tiles of 128: content GEMM + Ppos gather + online softmax
// + P@V. Scores never touch HBM.
// rel_shift linear trick: shifted[q][k] = Ppos_flat[q*(S-1) + S-1 + k - (k>q)],
// zeroed at k == q+1.  (branch2 addr == branch1 addr - 1; verified vs round-3
// scatter kernel which passed validation.)
// LDS: QUt 33.8K | KsPt union 67.6K (Ks 64x132 during QK, Pt 128x132 during PV)
//      | Vs 34.8K  => 136 KB, 1 block/CU, 8 waves.
// ---------------------------------------------------------------------------
__global__ __launch_bounds__(512)
void attn_fused(const float* __restrict__ qu, const float* __restrict__ kt,
                const float* __restrict__ vbuf, const float* __restrict__ ppos,
                float* __restrict__ ctx, int head_base)
{
    __shared__ float QUt[64 * 132];
    __shared__ float KsPt[128 * 132];
    __shared__ float Vs[128 * 68];

    const int t  = threadIdx.x;
    const int tx = t & 15;        // 16 col-groups (8 score cols / 4 ctx cols each)
    const int ty = t >> 4;        // 32 row-groups (4 q-rows each)
    const int z  = blockIdx.x >> 4;
    const int qt = blockIdx.x & 15;
    const int g  = head_base + z;
    const int q0 = qt * 128;

    const float* QU = qu   + (size_t)g * HEAD_ELEMS;
    const float* KT = kt   + (size_t)g * HEAD_ELEMS;   // [d][s]
    const float* V  = vbuf + (size_t)g * HEAD_ELEMS;   // [s][d]
    const float* Pg = ppos + (size_t)z * SS;

    // stage QU tile transposed: QUt[d][r] = QU[q0+r][d]
#pragma unroll
    for (int i = 0; i < 4; ++i) {
        int f = t + i * 512;
        int r = f >> 4, d4 = f & 15;
        float4 a = *(const float4*)(QU + (size_t)(q0 + r) * DHD + d4 * 4);
        QUt[(d4 * 4 + 0) * 132 + r] = a.x;
        QUt[(d4 * 4 + 1) * 132 + r] = a.y;
        QUt[(d4 * 4 + 2) * 132 + r] = a.z;
        QUt[(d4 * 4 + 3) * 132 + r] = a.w;
    }

    float m_run[4], l_run[4], acc[4][4];
#pragma unroll
    for (int i = 0; i < 4; ++i) {
        m_run[i] = -1e30f; l_run[i] = 0.f;
#pragma unroll
        for (int c = 0; c < 4; ++c) acc[i][c] = 0.f;
    }

    const float scale = 0.04419417382415922f;   // 1/sqrt(512)

    for (int k0 = 0; k0 < S_LEN; k0 += 128) {
        __syncthreads();   // prev Pt/Vs reads done; QUt visible on first iter
        // stage Ks[d][n] = KT[d][k0+n]
#pragma unroll
        for (int i = 0; i < 4; ++i) {
            int f = t + i * 512;
            int d = f >> 5, c4 = f & 31;
            *(float4*)&KsPt[d * 132 + c4 * 4] =
                *(const float4*)(KT + (size_t)d * S_LEN + k0 + c4 * 4);
        }
        // stage Vs[k][d]
#pragma unroll
        for (int i = 0; i < 4; ++i) {
            int f = t + i * 512;
            int r = f >> 4, d4 = f & 15;
            *(float4*)&Vs[r * 68 + d4 * 4] =
                *(const float4*)(V + (size_t)(k0 + r) * DHD + d4 * 4);
        }
        __syncthreads();

        // gather rel-shifted pos scores (issue VMEM early)
        float gpv[4][8];
#pragma unroll
        for (int i = 0; i < 4; ++i) {
            int q = q0 + ty * 4 + i;
            size_t base = (size_t)q * (S_LEN - 1) + (S_LEN - 1);
#pragma unroll
            for (int j = 0; j < 8; ++j) {
                int k = k0 + tx * 8 + j;
                int dq = k - q;
                float p = Pg[base + k - (dq >= 1 ? 1 : 0)];
                gpv[i][j] = (dq == 1) ? 0.f : p;
            }
        }

        // content scores: QU_tile @ K_tile^T   (K = 64 in one sweep)
        float sc[4][8];
#pragma unroll
        for (int i = 0; i < 4; ++i)
#pragma unroll
            for (int j = 0; j < 8; ++j) sc[i][j] = 0.f;

        for (int kc = 0; kc < 64; ++kc) {
            float a4[4], b8[8];
            *(float4*)&a4[0] = *(const float4*)&QUt[kc * 132 + ty * 4];
            *(float4*)&b8[0] = *(const float4*)&KsPt[kc * 132 + tx * 8];
            *(float4*)&b8[4] = *(const float4*)&KsPt[kc * 132 + tx * 8 + 4];
#pragma unroll
            for (int i = 0; i < 4; ++i)
#pragma unroll
                for (int j = 0; j < 8; ++j) sc[i][j] = fmaf(a4[i], b8[j], sc[i][j]);
        }

        // combine + scale + online softmax update (rows live in 16 lanes)
#pragma unroll
        for (int i = 0; i < 4; ++i) {
            float tm = -1e30f;
#pragma unroll
            for (int j = 0; j < 8; ++j) {
                sc[i][j] = (sc[i][j] + gpv[i][j]) * scale;
                tm = fmaxf(tm, sc[i][j]);
            }
            tm = fmaxf(tm, __shfl_xor(tm, 1));
            tm = fmaxf(tm, __shfl_xor(tm, 2));
            tm = fmaxf(tm, __shfl_xor(tm, 4));
            tm = fmaxf(tm, __shfl_xor(tm, 8));
            float m_new = fmaxf(m_run[i], tm);
            float alpha = __expf(m_run[i] - m_new);
            float rs = 0.f;
#pragma unroll
            for (int j = 0; j < 8; ++j) {
                sc[i][j] = __expf(sc[i][j] - m_new);
                rs += sc[i][j];
            }
            rs += __shfl_xor(rs, 1);
            rs += __shfl_xor(rs, 2);
            rs += __shfl_xor(rs, 4);
            rs += __shfl_xor(rs, 8);
            l_run[i] = l_run[i] * alpha + rs;
            m_run[i] = m_new;
#pragma unroll
            for (int c = 0; c < 4; ++c) acc[i][c] *= alpha;
        }

        __syncthreads();   // all reads of Ks complete before Pt overlay
        // write P^T into KsPt (swizzled to break bank conflicts)
#pragma unroll
        for (int j = 0; j < 8; ++j) {
            int k = tx * 8 + j;
            int qb = (ty * 4) ^ ((k & 24) >> 1);
#pragma unroll
            for (int i = 0; i < 4; ++i)
                KsPt[k * 132 + qb + i] = sc[i][j];
        }
        __syncthreads();

        // P @ V : acc[i][c] += Pt[kc][row] * Vs[kc][col]
        for (int kc = 0; kc < 128; ++kc) {
            float a4[4], b4[4];
            *(float4*)&a4[0] =
                *(const float4*)&KsPt[kc * 132 + ((ty * 4) ^ ((kc & 24) >> 1))];
            *(float4*)&b4[0] = *(const float4*)&Vs[kc * 68 + tx * 4];
#pragma unroll
            for (int i = 0; i < 4; ++i)
#pragma unroll
                for (int c = 0; c < 4; ++c) acc[i][c] = fmaf(a4[i], b4[c], acc[i][c]);
        }
    }

    // epilogue: normalize and store ctx[b][s][h*64+d]
    const int bb = g >> 3, h = g & 7;
#pragma unroll
    for (int i = 0; i < 4; ++i) {
        int q = q0 + ty * 4 + i;
        float inv = 1.f / l_run[i];
        float4 o = make_float4(acc[i][0] * inv, acc[i][1] * inv,
                               acc[i][2] * inv, acc[i][3] * inv);
        *(float4*)(ctx + ((size_t)(bb * S_LEN + q)) * DM + h * DHD + tx * 4) = o;
    }
}

// ---------------------------------------------------------------------------
// Output GEMM: out[4096,512] = ctx[4096,512] @ Wo + bo
// ---------------------------------------------------------------------------
__global__ __launch_bounds__(256)
void out_gemm(const float* __restrict__ ca,
              const float* __restrict__ Wo, const float* __restrict__ bo,
              float* __restrict__ out)
{
    __shared__ float Ast[32][132];
    __shared__ float Bs[32][132];
    const int t = threadIdx.x;
    const int tx = t & 15, ty = t >> 4;
    const int n0 = blockIdx.x * 128, m0 = blockIdx.y * 128;

    float acc[8][8];
#pragma unroll
    for (int i = 0; i < 8; ++i)
#pragma unroll
        for (int j = 0; j < 8; ++j) acc[i][j] = 0.f;

    for (int k0 = 0; k0 < 512; k0 += 32) {
#pragma unroll
        for (int i = 0; i < 4; ++i) {
            int f = t + i * 256;
            int row = f >> 3, kq = f & 7;
            float4 a4 = *(const float4*)(ca + (size_t)(m0 + row) * 512 + k0 + kq * 4);
            Ast[kq * 4 + 0][row] = a4.x; Ast[kq * 4 + 1][row] = a4.y;
            Ast[kq * 4 + 2][row] = a4.z; Ast[kq * 4 + 3][row] = a4.w;
        }
#pragma unroll
        for (int i = 0; i < 4; ++i) {
            int f = t + i * 256;
            int row = f >> 5, c4 = f & 31;
            *(float4*)&Bs[row][c4 * 4] =
                *(const float4*)(Wo + (size_t)(k0 + row) * 512 + n0 + c4 * 4);
        }
        __syncthreads();
#pragma unroll
        for (int kc = 0; kc < 32; ++kc) {
            float a[8], b[8];
            *(float4*)&a[0] = *(const float4*)&Ast[kc][ty * 8];
            *(float4*)&a[4] = *(const float4*)&Ast[kc][ty * 8 + 4];
            *(float4*)&b[0] = *(const float4*)&Bs[kc][tx * 8];
            *(float4*)&b[4] = *(const float4*)&Bs[kc][tx * 8 + 4];
#pragma unroll
            for (int i = 0; i < 8; ++i)
#pragma unroll
                for (int j = 0; j < 8; ++j) acc[i][j] = fmaf(a[i], b[j], acc[i][j]);
        }
        __syncthreads();
    }

#pragma unroll
    for (int i = 0; i < 8; ++i) {
        int gm = m0 + ty * 8 + i;
#pragma unroll
        for (int j4 = 0; j4 < 2; ++j4) {
            int gn = n0 + tx * 8 + j4 * 4;
            float4 bi = *(const float4*)(bo + gn);
            *(float4*)(out + (size_t)gm * 512 + gn) =
                make_float4(acc[i][j4 * 4 + 0] + bi.x, acc[i][j4 * 4 + 1] + bi.y,
                            acc[i][j4 * 4 + 2] + bi.z, acc[i][j4 * 4 + 3] + bi.w);
        }
    }
}

// Fallback when ws_size is insufficient: clean mismatch instead of OOB writes.
__global__ void zero_fill(float* __restrict__ p, int n)
{
    int i = blockIdx.x * 256 + threadIdx.x;
    if (i < n) p[i] = 0.f;
}

// ---------------------------------------------------------------------------
extern "C" void kernel_launch(void* const* d_in, const int* in_sizes, int n_in,
                              void* d_out, int out_size, void* d_ws, size_t ws_size,
                              hipStream_t stream)
{
    const float* x   = (const float*)d_in[0];
    const float* pos = (const float*)d_in[1];
    const float* Wq  = (const float*)d_in[2];
    const float* bq  = (const float*)d_in[3];
    const float* Wk  = (const float*)d_in[4];
    const float* bk  = (const float*)d_in[5];
    const float* Wv  = (const float*)d_in[6];
    const float* bv  = (const float*)d_in[7];
    const float* Wp  = (const float*)d_in[8];
    const float* u   = (const float*)d_in[9];
    const float* v   = (const float*)d_in[10];
    const float* Wo  = (const float*)d_in[11];
    const float* bo  = (const float*)d_in[12];
    float* ws  = (float*)d_ws;
    float* out = (float*)d_out;

    // Workspace guard: need OFF_P + >=1 head of Ppos (64 MB total).
    const size_t need_bytes = ((size_t)OFF_P + SS) * sizeof(float);
    if (ws_size < need_bytes) {
        zero_fill<<<(out_size + 255) / 256, 256, 0, stream>>>(out, out_size);
        return;
    }

    // 1. projections (modes 0..3 via blockIdx.z)
    proj_kernel<<<dim3(4, 32, 4), 256, 0, stream>>>(x, pos, Wq, bq, Wk, bk, Wv, bv,
                                                    Wp, u, v, ws);

    // 2. attention, in head-chunks sized to the workspace
    long ws_floats = (long)(ws_size / 4);
    long avail = ws_floats - (long)OFF_P;
    int c = (int)(avail / (long)SS);
    if (c < 1) c = 1;
    if (c > NBH) c = NBH;

    for (int g0 = 0; g0 < NBH; g0 += c) {
        int cc = (NBH - g0 < c) ? (NBH - g0) : c;
        pos_gemm<<<dim3(16, 16, cc), 256, 0, stream>>>(ws + OFF_QV, ws + OFF_PT,
                                                       ws + OFF_P, g0);
        attn_fused<<<dim3(cc * 16), 512, 0, stream>>>(ws + OFF_QU, ws + OFF_KT,
                                                      ws + OFF_V, ws + OFF_P,
                                                      ws + OFF_CTX, g0);
    }

    // 3. output projection
    out_gemm<<<dim3(4, 32, 1), 256, 0, stream>>>(ws + OFF_CTX, Wo, bo, out);
}

// Round 5
// 561.958 us; speedup vs baseline: 1.8730x; 1.7045x over previous
//
#include <hip/hip_runtime.h>
#include <hip/hip_bf16.h>
#include <hip/hip_fp16.h>
#include <math.h>

// Transformer-XL relative multi-head attention, MI355X. B=2,S=2048,D=512,H=8,dh=64.
// Round-5: bf16-MFMA flash attention core; fp32 projections; fp16 Ppos.
//  1. proj_kernel : x@Wq+bq -> QU(bf16,+u)/QV(fp32,+v); x@Wk+bk -> K(bf16,[s][d]);
//                   x@Wv+bv -> VT(bf16,[d][s]); pos@Wp -> PT(fp32,[d][s]).
//  2. per head-chunk:
//     a. pos_gemm : Ppos(fp16)[z][2048][2048] = QV_h @ PT_h
//     b. attn_fused: per (head, 64-row q-tile), 256 thr = 4 waves, k-tiles of 128.
//        QK^T via mfma_f32_16x16x32_bf16, + fp16 Ppos gather (rel-shift linear
//        trick, validated rounds 3-4), online softmax fp32, P(bf16)@V via MFMA.
//        LDS 62.4 KB -> 2 blocks/CU.
//  3. out_gemm : out = ctx @ Wo + bo (fp32).

#define S_LEN 2048
#define NH 8
#define DHD 64
#define DM 512
#define NBH 16
#define HEAD_ELEMS (S_LEN * DHD)
#define SS ((size_t)S_LEN * (size_t)S_LEN)

// workspace byte offsets
#define BY_QU  0u               // bf16 [16][2048][64]   4 MB
#define BY_K   4194304u         // bf16 [16][2048][64]   4 MB
#define BY_VT  8388608u         // bf16 [16][64][2048]   4 MB
#define BY_QV  12582912u        // fp32 [16][2048][64]   8 MB
#define BY_PT  20971520u        // fp32 [16][64][2048]   8 MB
#define BY_CTX 29360128u        // fp32 [2][2048][512]   8 MB
#define BY_PP  37748736u        // fp16 [c][2048][2048]  8.39 MB/head
#define PP_HEAD_BYTES 8388608u

typedef short v8s __attribute__((ext_vector_type(8)));
typedef float v4f __attribute__((ext_vector_type(4)));

static __device__ __forceinline__ unsigned short f2bf(float f) {
    __hip_bfloat16 h = __float2bfloat16(f);
    return *reinterpret_cast<unsigned short*>(&h);
}
static __device__ __forceinline__ unsigned short f2h(float f) {
    __half h = __float2half(f);
    return *reinterpret_cast<unsigned short*>(&h);
}
static __device__ __forceinline__ float h2f(unsigned short u) {
    __half h = *reinterpret_cast<__half*>(&u);
    return __half2float(h);
}

// ---------------------------------------------------------------------------
// Projections: C[4096,512] = A[4096,512] @ W[512,512] (+bias), mode via blockIdx.z.
// ---------------------------------------------------------------------------
__global__ __launch_bounds__(256)
void proj_kernel(const float* __restrict__ x, const float* __restrict__ pos,
                 const float* __restrict__ Wq, const float* __restrict__ bq,
                 const float* __restrict__ Wk, const float* __restrict__ bk,
                 const float* __restrict__ Wv, const float* __restrict__ bvp,
                 const float* __restrict__ Wp,
                 const float* __restrict__ uvec, const float* __restrict__ vvec,
                 char* __restrict__ wsb)
{
    __shared__ float Ast[32][132];
    __shared__ float Bs[32][132];
    const int t = threadIdx.x;
    const int tx = t & 15, ty = t >> 4;
    const int mode = blockIdx.z;
    const int n0 = blockIdx.x * 128, m0 = blockIdx.y * 128;

    const float* A = (mode == 3) ? pos : x;
    const float* W = (mode == 0) ? Wq : (mode == 1) ? Wk : (mode == 2) ? Wv : Wp;

    float acc[8][8];
#pragma unroll
    for (int i = 0; i < 8; ++i)
#pragma unroll
        for (int j = 0; j < 8; ++j) acc[i][j] = 0.f;

    for (int k0 = 0; k0 < 512; k0 += 32) {
#pragma unroll
        for (int i = 0; i < 4; ++i) {
            int f = t + i * 256;
            int row = f >> 3, kq = f & 7;
            float4 a4 = *(const float4*)(A + (size_t)(m0 + row) * 512 + k0 + kq * 4);
            Ast[kq * 4 + 0][row] = a4.x; Ast[kq * 4 + 1][row] = a4.y;
            Ast[kq * 4 + 2][row] = a4.z; Ast[kq * 4 + 3][row] = a4.w;
        }
#pragma unroll
        for (int i = 0; i < 4; ++i) {
            int f = t + i * 256;
            int row = f >> 5, c4 = f & 31;
            *(float4*)&Bs[row][c4 * 4] =
                *(const float4*)(W + (size_t)(k0 + row) * 512 + n0 + c4 * 4);
        }
        __syncthreads();
#pragma unroll
        for (int kc = 0; kc < 32; ++kc) {
            float a[8], b[8];
            *(float4*)&a[0] = *(const float4*)&Ast[kc][ty * 8];
            *(float4*)&a[4] = *(const float4*)&Ast[kc][ty * 8 + 4];
            *(float4*)&b[0] = *(const float4*)&Bs[kc][tx * 8];
            *(float4*)&b[4] = *(const float4*)&Bs[kc][tx * 8 + 4];
#pragma unroll
            for (int i = 0; i < 8; ++i)
#pragma unroll
                for (int j = 0; j < 8; ++j) acc[i][j] = fmaf(a[i], b[j], acc[i][j]);
        }
        __syncthreads();
    }

    const int bb = m0 >> 11;

    if (mode == 0) {
        unsigned short* qu = (unsigned short*)(wsb + BY_QU);
        float* qv = (float*)(wsb + BY_QV);
#pragma unroll
        for (int i = 0; i < 8; ++i) {
            int gm = m0 + ty * 8 + i, srow = gm & 2047;
#pragma unroll
            for (int j4 = 0; j4 < 2; ++j4) {
                int gn = n0 + tx * 8 + j4 * 4;
                int h = gn >> 6, d = gn & 63;
                float4 bi = *(const float4*)(bq + gn);
                float4 uu = *(const float4*)(uvec + gn);
                float4 vv = *(const float4*)(vvec + gn);
                float c0 = acc[i][j4 * 4 + 0] + bi.x, c1 = acc[i][j4 * 4 + 1] + bi.y;
                float c2 = acc[i][j4 * 4 + 2] + bi.z, c3 = acc[i][j4 * 4 + 3] + bi.w;
                size_t o = ((size_t)(bb * NH + h) * S_LEN + srow) * DHD + d;
                ushort4 pk;
                pk.x = f2bf(c0 + uu.x); pk.y = f2bf(c1 + uu.y);
                pk.z = f2bf(c2 + uu.z); pk.w = f2bf(c3 + uu.w);
                *(ushort4*)(qu + o) = pk;
                *(float4*)(qv + o) = make_float4(c0 + vv.x, c1 + vv.y, c2 + vv.z, c3 + vv.w);
            }
        }
    } else if (mode == 1) {      // K bf16 [bh][s][d]
        unsigned short* kd = (unsigned short*)(wsb + BY_K);
#pragma unroll
        for (int i = 0; i < 8; ++i) {
            int gm = m0 + ty * 8 + i, srow = gm & 2047;
#pragma unroll
            for (int j4 = 0; j4 < 2; ++j4) {
                int gn = n0 + tx * 8 + j4 * 4;
                int h = gn >> 6, d = gn & 63;
                float4 bi = *(const float4*)(bk + gn);
                size_t o = ((size_t)(bb * NH + h) * S_LEN + srow) * DHD + d;
                ushort4 pk;
                pk.x = f2bf(acc[i][j4 * 4 + 0] + bi.x);
                pk.y = f2bf(acc[i][j4 * 4 + 1] + bi.y);
                pk.z = f2bf(acc[i][j4 * 4 + 2] + bi.z);
                pk.w = f2bf(acc[i][j4 * 4 + 3] + bi.w);
                *(ushort4*)(kd + o) = pk;
            }
        }
    } else if (mode == 2) {      // VT bf16 [bh][d][s]
        unsigned short* vt = (unsigned short*)(wsb + BY_VT);
#pragma unroll
        for (int j = 0; j < 8; ++j) {
            int gn = n0 + tx * 8 + j;
            int h = gn >> 6, d = gn & 63;
            float bval = bvp[gn];
            size_t rowbase = ((size_t)(bb * NH + h) * DHD + d) * S_LEN;
#pragma unroll
            for (int i4 = 0; i4 < 2; ++i4) {
                int srow = (m0 & 2047) + ty * 8 + i4 * 4;
                ushort4 pk;
                pk.x = f2bf(acc[i4 * 4 + 0][j] + bval);
                pk.y = f2bf(acc[i4 * 4 + 1][j] + bval);
                pk.z = f2bf(acc[i4 * 4 + 2][j] + bval);
                pk.w = f2bf(acc[i4 * 4 + 3][j] + bval);
                *(ushort4*)(vt + rowbase + srow) = pk;
            }
        }
    } else {                     // PT fp32 [bh][d][s]
        float* dst = (float*)(wsb + BY_PT);
#pragma unroll
        for (int j = 0; j < 8; ++j) {
            int gn = n0 + tx * 8 + j;
            int h = gn >> 6, d = gn & 63;
            size_t rowbase = ((size_t)(bb * NH + h) * DHD + d) * S_LEN;
#pragma unroll
            for (int i4 = 0; i4 < 2; ++i4) {
                int srow = (m0 & 2047) + ty * 8 + i4 * 4;
                float4 o4 = make_float4(acc[i4 * 4 + 0][j], acc[i4 * 4 + 1][j],
                                        acc[i4 * 4 + 2][j], acc[i4 * 4 + 3][j]);
                *(float4*)(dst + rowbase + srow) = o4;
            }
        }
    }
}

// ---------------------------------------------------------------------------
// pos GEMM: Ppos(fp16)[z][2048][2048] = QV_h[2048,64] @ PT_h[64,2048].
// ---------------------------------------------------------------------------
__global__ __launch_bounds__(256)
void pos_gemm(const float* __restrict__ Aq, const float* __restrict__ Bt,
              unsigned short* __restrict__ pp, int head_base)
{
    __shared__ float Ast[32][132];
    __shared__ float Bs[32][132];
    const int t = threadIdx.x;
    const int tx = t & 15, ty = t >> 4;
    const int n0 = blockIdx.x * 128, m0 = blockIdx.y * 128, z = blockIdx.z;
    const int g = head_base + z;
    const float* A  = Aq + (size_t)g * HEAD_ELEMS;
    const float* Bb = Bt + (size_t)g * HEAD_ELEMS;
    unsigned short* out = pp + (size_t)z * SS;

    float acc[8][8];
#pragma unroll
    for (int i = 0; i < 8; ++i)
#pragma unroll
        for (int j = 0; j < 8; ++j) acc[i][j] = 0.f;

    for (int k0 = 0; k0 < 64; k0 += 32) {
#pragma unroll
        for (int i = 0; i < 4; ++i) {
            int f = t + i * 256;
            int row = f >> 3, kq = f & 7;
            float4 a4 = *(const float4*)(A + (size_t)(m0 + row) * DHD + k0 + kq * 4);
            Ast[kq * 4 + 0][row] = a4.x; Ast[kq * 4 + 1][row] = a4.y;
            Ast[kq * 4 + 2][row] = a4.z; Ast[kq * 4 + 3][row] = a4.w;
        }
#pragma unroll
        for (int i = 0; i < 4; ++i) {
            int f = t + i * 256;
            int row = f >> 5, c4 = f & 31;
            *(float4*)&Bs[row][c4 * 4] =
                *(const float4*)(Bb + (size_t)(k0 + row) * S_LEN + n0 + c4 * 4);
        }
        __syncthreads();
#pragma unroll
        for (int kc = 0; kc < 32; ++kc) {
            float a[8], b[8];
            *(float4*)&a[0] = *(const float4*)&Ast[kc][ty * 8];
            *(float4*)&a[4] = *(const float4*)&Ast[kc][ty * 8 + 4];
            *(float4*)&b[0] = *(const float4*)&Bs[kc][tx * 8];
            *(float4*)&b[4] = *(const float4*)&Bs[kc][tx * 8 + 4];
#pragma unroll
            for (int i = 0; i < 8; ++i)
#pragma unroll
                for (int j = 0; j < 8; ++j) acc[i][j] = fmaf(a[i], b[j], acc[i][j]);
        }
        __syncthreads();
    }

#pragma unroll
    for (int i = 0; i < 8; ++i) {
        int gm = m0 + ty * 8 + i;
#pragma unroll
        for (int j4 = 0; j4 < 2; ++j4) {
            int gn = n0 + tx * 8 + j4 * 4;
            ushort4 pk;
            pk.x = f2h(acc[i][j4 * 4 + 0]); pk.y = f2h(acc[i][j4 * 4 + 1]);
            pk.z = f2h(acc[i][j4 * 4 + 2]); pk.w = f2h(acc[i][j4 * 4 + 3]);
            *(ushort4*)(out + (size_t)gm * S_LEN + gn) = pk;
        }
    }
}

// ---------------------------------------------------------------------------
// Fused bf16-MFMA flash attention.
// Block = (head z, 64-row q-tile), 256 thr = 4 waves; wave w owns q-rows
// [w*16, w*16+16).  K-tiles of 128.  mfma_f32_16x16x32_bf16:
//   A[m=lane&15][k=quad*8+j], B[k=quad*8+j][n=lane&15], C/D row=quad*4+reg,
//   col=lane&15  (verified layouts, learn_hip m89/m120).
// LDS strides padded (+8 halfs) so 16-row fragment reads land 4 banks apart.
// ---------------------------------------------------------------------------
__global__ __launch_bounds__(256)
void attn_fused(const unsigned short* __restrict__ qu,
                const unsigned short* __restrict__ kdat,
                const unsigned short* __restrict__ vtg,
                const unsigned short* __restrict__ pp,
                float* __restrict__ ctx, int head_base)
{
    __shared__ unsigned short Qs[64 * 72];
    __shared__ unsigned short Ks[128 * 72];
    __shared__ unsigned short Vt[64 * 136];
    __shared__ unsigned short Sp[64 * 136];

    const int t = threadIdx.x;
    const int wave = t >> 6, lane = t & 63;
    const int quad = lane >> 4, l16 = lane & 15;
    const int z = blockIdx.x >> 5, qt = blockIdx.x & 31;
    const int g = head_base + z;
    const int q0 = qt * 64;

    const unsigned short* QU = qu   + (size_t)g * HEAD_ELEMS;   // [s][d] bf16
    const unsigned short* Kg = kdat + (size_t)g * HEAD_ELEMS;   // [s][d] bf16
    const unsigned short* Vg = vtg  + (size_t)g * HEAD_ELEMS;   // [d][s] bf16
    const unsigned short* Pg = pp   + (size_t)z * SS;           // fp16

    // stage Q tile once: Qs[r][d], stride 72
#pragma unroll
    for (int i = 0; i < 2; ++i) {
        int f = t + i * 256;
        int r = f >> 3, c8 = f & 7;
        *(uint4*)&Qs[r * 72 + c8 * 8] =
            *(const uint4*)(QU + (size_t)(q0 + r) * DHD + c8 * 8);
    }

    float m_run[4], l_run[4];
    v4f accv[4];
#pragma unroll
    for (int r = 0; r < 4; ++r) {
        m_run[r] = -1e30f; l_run[r] = 0.f;
        accv[r] = (v4f){0.f, 0.f, 0.f, 0.f};
    }
    const float scale = 0.04419417382415922f;   // 1/sqrt(512)

    for (int k0 = 0; k0 < S_LEN; k0 += 128) {
        __syncthreads();   // prior PV reads done (and Qs visible, iter 0)
        // stage Ks[key][d] (128x64), stride 72
#pragma unroll
        for (int i = 0; i < 4; ++i) {
            int f = t + i * 256;
            int r = f >> 3, c8 = f & 7;
            *(uint4*)&Ks[r * 72 + c8 * 8] =
                *(const uint4*)(Kg + (size_t)(k0 + r) * DHD + c8 * 8);
        }
        // stage Vt[d][k] (64x128), stride 136
#pragma unroll
        for (int i = 0; i < 4; ++i) {
            int f = t + i * 256;
            int d = f >> 4, c8 = f & 15;
            *(uint4*)&Vt[d * 136 + c8 * 8] =
                *(const uint4*)(Vg + (size_t)d * S_LEN + k0 + c8 * 8);
        }
        __syncthreads();

        // fp16 Ppos gather via rel-shift linear trick (validated r3/r4)
        float gp[8][4];
#pragma unroll
        for (int nt = 0; nt < 8; ++nt) {
            int k = k0 + nt * 16 + l16;
#pragma unroll
            for (int reg = 0; reg < 4; ++reg) {
                int q = q0 + wave * 16 + quad * 4 + reg;
                int dq = k - q;
                size_t addr = (size_t)q * (S_LEN - 1) + (S_LEN - 1) + k - (dq >= 1 ? 1 : 0);
                float pv = h2f(Pg[addr]);
                gp[nt][reg] = (dq == 1) ? 0.f : pv;
            }
        }

        // QK^T: S[16 q][128 k] per wave
        v8s aq0 = *(const v8s*)&Qs[(wave * 16 + l16) * 72 + quad * 8];
        v8s aq1 = *(const v8s*)&Qs[(wave * 16 + l16) * 72 + 32 + quad * 8];
        v4f sacc[8];
#pragma unroll
        for (int nt = 0; nt < 8; ++nt) {
            v8s b0 = *(const v8s*)&Ks[(nt * 16 + l16) * 72 + quad * 8];
            v8s b1 = *(const v8s*)&Ks[(nt * 16 + l16) * 72 + 32 + quad * 8];
            v4f c = (v4f){0.f, 0.f, 0.f, 0.f};
            c = __builtin_amdgcn_mfma_f32_16x16x32_bf16(aq0, b0, c, 0, 0, 0);
            c = __builtin_amdgcn_mfma_f32_16x16x32_bf16(aq1, b1, c, 0, 0, 0);
            sacc[nt] = c;
        }

        // online softmax (rows = quad*4+reg; cols across 16 lanes x 8 nt)
        float pr[8][4];
#pragma unroll
        for (int reg = 0; reg < 4; ++reg) {
            float s[8]; float tm = -1e30f;
#pragma unroll
            for (int nt = 0; nt < 8; ++nt) {
                s[nt] = (sacc[nt][reg] + gp[nt][reg]) * scale;
                tm = fmaxf(tm, s[nt]);
            }
            tm = fmaxf(tm, __shfl_xor(tm, 1));
            tm = fmaxf(tm, __shfl_xor(tm, 2));
            tm = fmaxf(tm, __shfl_xor(tm, 4));
            tm = fmaxf(tm, __shfl_xor(tm, 8));
            float mn = fmaxf(m_run[reg], tm);
            float al = __expf(m_run[reg] - mn);
            float rs = 0.f;
#pragma unroll
            for (int nt = 0; nt < 8; ++nt) {
                pr[nt][reg] = __expf(s[nt] - mn);
                rs += pr[nt][reg];
            }
            rs += __shfl_xor(rs, 1);
            rs += __shfl_xor(rs, 2);
            rs += __shfl_xor(rs, 4);
            rs += __shfl_xor(rs, 8);
            l_run[reg] = l_run[reg] * al + rs;
            m_run[reg] = mn;
#pragma unroll
            for (int ntd = 0; ntd < 4; ++ntd) accv[ntd][reg] *= al;
        }

        // P -> bf16 into Sp (wave-private rows; LDS ops in-order per wave)
#pragma unroll
        for (int nt = 0; nt < 8; ++nt)
#pragma unroll
            for (int reg = 0; reg < 4; ++reg)
                Sp[(wave * 16 + quad * 4 + reg) * 136 + nt * 16 + l16] = f2bf(pr[nt][reg]);

        // PV: ctx[16 q][64 d] += P[16][128] @ V[128][64]
#pragma unroll
        for (int c = 0; c < 4; ++c) {
            v8s ap = *(const v8s*)&Sp[(wave * 16 + l16) * 136 + c * 32 + quad * 8];
#pragma unroll
            for (int ntd = 0; ntd < 4; ++ntd) {
                v8s bv8 = *(const v8s*)&Vt[(ntd * 16 + l16) * 136 + c * 32 + quad * 8];
                accv[ntd] = __builtin_amdgcn_mfma_f32_16x16x32_bf16(ap, bv8, accv[ntd], 0, 0, 0);
            }
        }
    }

    // epilogue: normalize, store ctx[b][s][h*64+d] fp32
    const int bb = g >> 3, h = g & 7;
#pragma unroll
    for (int reg = 0; reg < 4; ++reg) {
        int q = q0 + wave * 16 + quad * 4 + reg;
        float inv = 1.f / l_run[reg];
#pragma unroll
        for (int ntd = 0; ntd < 4; ++ntd) {
            ctx[((size_t)(bb * S_LEN + q)) * DM + h * DHD + ntd * 16 + l16] =
                accv[ntd][reg] * inv;
        }
    }
}

// ---------------------------------------------------------------------------
// Output GEMM: out[4096,512] = ctx @ Wo + bo (fp32)
// ---------------------------------------------------------------------------
__global__ __launch_bounds__(256)
void out_gemm(const float* __restrict__ ca,
              const float* __restrict__ Wo, const float* __restrict__ bo,
              float* __restrict__ out)
{
    __shared__ float Ast[32][132];
    __shared__ float Bs[32][132];
    const int t = threadIdx.x;
    const int tx = t & 15, ty = t >> 4;
    const int n0 = blockIdx.x * 128, m0 = blockIdx.y * 128;

    float acc[8][8];
#pragma unroll
    for (int i = 0; i < 8; ++i)
#pragma unroll
        for (int j = 0; j < 8; ++j) acc[i][j] = 0.f;

    for (int k0 = 0; k0 < 512; k0 += 32) {
#pragma unroll
        for (int i = 0; i < 4; ++i) {
            int f = t + i * 256;
            int row = f >> 3, kq = f & 7;
            float4 a4 = *(const float4*)(ca + (size_t)(m0 + row) * 512 + k0 + kq * 4);
            Ast[kq * 4 + 0][row] = a4.x; Ast[kq * 4 + 1][row] = a4.y;
            Ast[kq * 4 + 2][row] = a4.z; Ast[kq * 4 + 3][row] = a4.w;
        }
#pragma unroll
        for (int i = 0; i < 4; ++i) {
            int f = t + i * 256;
            int row = f >> 5, c4 = f & 31;
            *(float4*)&Bs[row][c4 * 4] =
                *(const float4*)(Wo + (size_t)(k0 + row) * 512 + n0 + c4 * 4);
        }
        __syncthreads();
#pragma unroll
        for (int kc = 0; kc < 32; ++kc) {
            float a[8], b[8];
            *(float4*)&a[0] = *(const float4*)&Ast[kc][ty * 8];
            *(float4*)&a[4] = *(const float4*)&Ast[kc][ty * 8 + 4];
            *(float4*)&b[0] = *(const float4*)&Bs[kc][tx * 8];
            *(float4*)&b[4] = *(const float4*)&Bs[kc][tx * 8 + 4];
#pragma unroll
            for (int i = 0; i < 8; ++i)
#pragma unroll
                for (int j = 0; j < 8; ++j) acc[i][j] = fmaf(a[i], b[j], acc[i][j]);
        }
        __syncthreads();
    }

#pragma unroll
    for (int i = 0; i < 8; ++i) {
        int gm = m0 + ty * 8 + i;
#pragma unroll
        for (int j4 = 0; j4 < 2; ++j4) {
            int gn = n0 + tx * 8 + j4 * 4;
            float4 bi = *(const float4*)(bo + gn);
            *(float4*)(out + (size_t)gm * 512 + gn) =
                make_float4(acc[i][j4 * 4 + 0] + bi.x, acc[i][j4 * 4 + 1] + bi.y,
                            acc[i][j4 * 4 + 2] + bi.z, acc[i][j4 * 4 + 3] + bi.w);
        }
    }
}

// Fallback when ws_size is insufficient: clean mismatch instead of OOB writes.
__global__ void zero_fill(float* __restrict__ p, int n)
{
    int i = blockIdx.x * 256 + threadIdx.x;
    if (i < n) p[i] = 0.f;
}

// ---------------------------------------------------------------------------
extern "C" void kernel_launch(void* const* d_in, const int* in_sizes, int n_in,
                              void* d_out, int out_size, void* d_ws, size_t ws_size,
                              hipStream_t stream)
{
    const float* x   = (const float*)d_in[0];
    const float* pos = (const float*)d_in[1];
    const float* Wq  = (const float*)d_in[2];
    const float* bq  = (const float*)d_in[3];
    const float* Wk  = (const float*)d_in[4];
    const float* bk  = (const float*)d_in[5];
    const float* Wv  = (const float*)d_in[6];
    const float* bv  = (const float*)d_in[7];
    const float* Wp  = (const float*)d_in[8];
    const float* u   = (const float*)d_in[9];
    const float* v   = (const float*)d_in[10];
    const float* Wo  = (const float*)d_in[11];
    const float* bo  = (const float*)d_in[12];
    char* wsb  = (char*)d_ws;
    float* out = (float*)d_out;

    // Workspace guard: need BY_PP + >=1 head of fp16 Ppos (44 MB min).
    if (ws_size < (size_t)BY_PP + PP_HEAD_BYTES) {
        zero_fill<<<(out_size + 255) / 256, 256, 0, stream>>>(out, out_size);
        return;
    }

    // 1. projections
    proj_kernel<<<dim3(4, 32, 4), 256, 0, stream>>>(x, pos, Wq, bq, Wk, bk, Wv, bv,
                                                    Wp, u, v, wsb);

    // 2. attention in head-chunks sized to workspace
    int c = (int)((ws_size - (size_t)BY_PP) / (size_t)PP_HEAD_BYTES);
    if (c < 1) c = 1;
    if (c > NBH) c = NBH;

    for (int g0 = 0; g0 < NBH; g0 += c) {
        int cc = (NBH - g0 < c) ? (NBH - g0) : c;
        pos_gemm<<<dim3(16, 16, cc), 256, 0, stream>>>(
            (const float*)(wsb + BY_QV), (const float*)(wsb + BY_PT),
            (unsigned short*)(wsb + BY_PP), g0);
        attn_fused<<<dim3(cc * 32), 256, 0, stream>>>(
            (const unsigned short*)(wsb + BY_QU),
            (const unsigned short*)(wsb + BY_K),
            (const unsigned short*)(wsb + BY_VT),
            (const unsigned short*)(wsb + BY_PP),
            (float*)(wsb + BY_CTX), g0);
    }

    // 3. output projection
    out_gemm<<<dim3(4, 32, 1), 256, 0, stream>>>((const float*)(wsb + BY_CTX),
                                                 Wo, bo, out);
}

// Round 6
// 478.503 us; speedup vs baseline: 2.1997x; 1.1744x over previous
//
#include <hip/hip_runtime.h>
#include <hip/hip_fp16.h>
#include <math.h>

// Transformer-XL relative multi-head attention, MI355X. B=2,S=2048,D=512,H=8,dh=64.
// Round-6: barrier-free wave-autonomous flash attention (split-K=2) + fp16-MFMA
// pos GEMM. All MFMA inputs fp16 (better mantissa than bf16; same layouts).
//  1. proj_kernel (fp32 VALU): x@Wq+bq -> QU(+u)/QV(+v) fp16 [s][d];
//     x@Wk+bk -> K fp16 [s][d]; x@Wv+bv -> VT fp16 [d][s]; pos@Wp -> Pb fp16 [s][d].
//  2. per head-chunk:
//     a. pos_gemm  : Ppos(fp16)[z][2048][2048] = QV_h @ Pb_h^T  (MFMA, no LDS)
//     b. attn_fused: 4 waves/block = 2 q-groups x 2 k-halves; each wave owns 16 q
//        rows and 1024 keys, loops 8 k-tiles of 128 with NO barriers (Q/K/V frags
//        straight from global, wave-private LDS only for the P C->A transpose).
//        Rel-shift fp16 Ppos gather via the flat-index trick (validated r3-r5).
//        End: one barrier, flash-merge of the two k-halves, fp32 ctx store.
//  3. out_gemm (fp32): out = ctx @ Wo + bo.

#define S_LEN 2048
#define NH 8
#define DHD 64
#define DM 512
#define NBH 16
#define HEAD_ELEMS (S_LEN * DHD)
#define SS ((size_t)S_LEN * (size_t)S_LEN)

// workspace byte offsets
#define BY_QU  0u               // fp16 [16][2048][64]  4 MB
#define BY_QV  4194304u         // fp16 [16][2048][64]  4 MB
#define BY_K   8388608u         // fp16 [16][2048][64]  4 MB
#define BY_VT  12582912u        // fp16 [16][64][2048]  4 MB
#define BY_PB  16777216u        // fp16 [16][2048][64]  4 MB
#define BY_CTX 20971520u        // fp32 [2][2048][512]  8 MB
#define BY_PP  29360128u        // fp16 [c][2048][2048] 8.39 MB/head
#define PP_HEAD_BYTES 8388608u

typedef short v8s __attribute__((ext_vector_type(8)));
typedef float v4f __attribute__((ext_vector_type(4)));

static __device__ __forceinline__ unsigned short f2h(float f) {
    __half h = __float2half(f);
    return *reinterpret_cast<unsigned short*>(&h);
}
static __device__ __forceinline__ float h2f(unsigned short u) {
    __half h = *reinterpret_cast<__half*>(&u);
    return __half2float(h);
}

// ---------------------------------------------------------------------------
// Projections (fp32 compute): C[4096,512] = A @ W (+bias), mode via blockIdx.z.
// ---------------------------------------------------------------------------
__global__ __launch_bounds__(256)
void proj_kernel(const float* __restrict__ x, const float* __restrict__ pos,
                 const float* __restrict__ Wq, const float* __restrict__ bq,
                 const float* __restrict__ Wk, const float* __restrict__ bk,
                 const float* __restrict__ Wv, const float* __restrict__ bvp,
                 const float* __restrict__ Wp,
                 const float* __restrict__ uvec, const float* __restrict__ vvec,
                 char* __restrict__ wsb)
{
    __shared__ float Ast[32][132];
    __shared__ float Bs[32][132];
    const int t = threadIdx.x;
    const int tx = t & 15, ty = t >> 4;
    const int mode = blockIdx.z;
    const int n0 = blockIdx.x * 128, m0 = blockIdx.y * 128;

    const float* A = (mode == 3) ? pos : x;
    const float* W = (mode == 0) ? Wq : (mode == 1) ? Wk : (mode == 2) ? Wv : Wp;

    float acc[8][8];
#pragma unroll
    for (int i = 0; i < 8; ++i)
#pragma unroll
        for (int j = 0; j < 8; ++j) acc[i][j] = 0.f;

    for (int k0 = 0; k0 < 512; k0 += 32) {
#pragma unroll
        for (int i = 0; i < 4; ++i) {
            int f = t + i * 256;
            int row = f >> 3, kq = f & 7;
            float4 a4 = *(const float4*)(A + (size_t)(m0 + row) * 512 + k0 + kq * 4);
            Ast[kq * 4 + 0][row] = a4.x; Ast[kq * 4 + 1][row] = a4.y;
            Ast[kq * 4 + 2][row] = a4.z; Ast[kq * 4 + 3][row] = a4.w;
        }
#pragma unroll
        for (int i = 0; i < 4; ++i) {
            int f = t + i * 256;
            int row = f >> 5, c4 = f & 31;
            *(float4*)&Bs[row][c4 * 4] =
                *(const float4*)(W + (size_t)(k0 + row) * 512 + n0 + c4 * 4);
        }
        __syncthreads();
#pragma unroll
        for (int kc = 0; kc < 32; ++kc) {
            float a[8], b[8];
            *(float4*)&a[0] = *(const float4*)&Ast[kc][ty * 8];
            *(float4*)&a[4] = *(const float4*)&Ast[kc][ty * 8 + 4];
            *(float4*)&b[0] = *(const float4*)&Bs[kc][tx * 8];
            *(float4*)&b[4] = *(const float4*)&Bs[kc][tx * 8 + 4];
#pragma unroll
            for (int i = 0; i < 8; ++i)
#pragma unroll
                for (int j = 0; j < 8; ++j) acc[i][j] = fmaf(a[i], b[j], acc[i][j]);
        }
        __syncthreads();
    }

    const int bb = m0 >> 11;

    if (mode == 0) {
        unsigned short* qu = (unsigned short*)(wsb + BY_QU);
        unsigned short* qv = (unsigned short*)(wsb + BY_QV);
#pragma unroll
        for (int i = 0; i < 8; ++i) {
            int gm = m0 + ty * 8 + i, srow = gm & 2047;
#pragma unroll
            for (int j4 = 0; j4 < 2; ++j4) {
                int gn = n0 + tx * 8 + j4 * 4;
                int h = gn >> 6, d = gn & 63;
                float4 bi = *(const float4*)(bq + gn);
                float4 uu = *(const float4*)(uvec + gn);
                float4 vv = *(const float4*)(vvec + gn);
                float c0 = acc[i][j4 * 4 + 0] + bi.x, c1 = acc[i][j4 * 4 + 1] + bi.y;
                float c2 = acc[i][j4 * 4 + 2] + bi.z, c3 = acc[i][j4 * 4 + 3] + bi.w;
                size_t o = ((size_t)(bb * NH + h) * S_LEN + srow) * DHD + d;
                ushort4 pu, pv2;
                pu.x = f2h(c0 + uu.x); pu.y = f2h(c1 + uu.y);
                pu.z = f2h(c2 + uu.z); pu.w = f2h(c3 + uu.w);
                pv2.x = f2h(c0 + vv.x); pv2.y = f2h(c1 + vv.y);
                pv2.z = f2h(c2 + vv.z); pv2.w = f2h(c3 + vv.w);
                *(ushort4*)(qu + o) = pu;
                *(ushort4*)(qv + o) = pv2;
            }
        }
    } else if (mode == 1 || mode == 3) {   // K / Pb fp16 [bh][s][d]
        unsigned short* dst = (unsigned short*)(wsb + (mode == 1 ? BY_K : BY_PB));
        const float* bias = (mode == 1) ? bk : nullptr;
#pragma unroll
        for (int i = 0; i < 8; ++i) {
            int gm = m0 + ty * 8 + i, srow = gm & 2047;
#pragma unroll
            for (int j4 = 0; j4 < 2; ++j4) {
                int gn = n0 + tx * 8 + j4 * 4;
                int h = gn >> 6, d = gn & 63;
                float4 bi = bias ? *(const float4*)(bias + gn)
                                 : make_float4(0.f, 0.f, 0.f, 0.f);
                size_t o = ((size_t)(bb * NH + h) * S_LEN + srow) * DHD + d;
                ushort4 pk;
                pk.x = f2h(acc[i][j4 * 4 + 0] + bi.x);
                pk.y = f2h(acc[i][j4 * 4 + 1] + bi.y);
                pk.z = f2h(acc[i][j4 * 4 + 2] + bi.z);
                pk.w = f2h(acc[i][j4 * 4 + 3] + bi.w);
                *(ushort4*)(dst + o) = pk;
            }
        }
    } else {                               // VT fp16 [bh][d][s]
        unsigned short* vt = (unsigned short*)(wsb + BY_VT);
#pragma unroll
        for (int j = 0; j < 8; ++j) {
            int gn = n0 + tx * 8 + j;
            int h = gn >> 6, d = gn & 63;
            float bval = bvp[gn];
            size_t rowbase = ((size_t)(bb * NH + h) * DHD + d) * S_LEN;
#pragma unroll
            for (int i4 = 0; i4 < 2; ++i4) {
                int srow = (m0 & 2047) + ty * 8 + i4 * 4;
                ushort4 pk;
                pk.x = f2h(acc[i4 * 4 + 0][j] + bval);
                pk.y = f2h(acc[i4 * 4 + 1][j] + bval);
                pk.z = f2h(acc[i4 * 4 + 2][j] + bval);
                pk.w = f2h(acc[i4 * 4 + 3][j] + bval);
                *(ushort4*)(vt + rowbase + srow) = pk;
            }
        }
    }
}

// ---------------------------------------------------------------------------
// pos GEMM via fp16 MFMA, no LDS: Ppos[z] = QV_h[2048,64] @ Pb_h[2048,64]^T.
// Block 256 thr = 2x2 waves, each wave 64x64; A/B frags 16B-contiguous global.
// ---------------------------------------------------------------------------
__global__ __launch_bounds__(256)
void pos_gemm(const unsigned short* __restrict__ qv,
              const unsigned short* __restrict__ pb,
              unsigned short* __restrict__ pp, int head_base)
{
    const int t = threadIdx.x;
    const int wave = t >> 6, lane = t & 63;
    const int quad = lane >> 4, l16 = lane & 15;
    const int wm = wave >> 1, wn = wave & 1;
    const int z = blockIdx.z, g = head_base + z;
    const int m0 = blockIdx.y * 128 + wm * 64;
    const int n0 = blockIdx.x * 128 + wn * 64;

    const unsigned short* A = qv + (size_t)g * HEAD_ELEMS;   // [s][d]
    const unsigned short* B = pb + (size_t)g * HEAD_ELEMS;   // [s][d] = B^T layout
    unsigned short* out = pp + (size_t)z * SS;

    v8s af[4][2], bf[4][2];
#pragma unroll
    for (int i = 0; i < 4; ++i)
#pragma unroll
        for (int kk = 0; kk < 2; ++kk) {
            af[i][kk] = *(const v8s*)(A + (size_t)(m0 + i * 16 + l16) * DHD + kk * 32 + quad * 8);
            bf[i][kk] = *(const v8s*)(B + (size_t)(n0 + i * 16 + l16) * DHD + kk * 32 + quad * 8);
        }

#pragma unroll
    for (int i = 0; i < 4; ++i)
#pragma unroll
        for (int j = 0; j < 4; ++j) {
            v4f c = (v4f){0.f, 0.f, 0.f, 0.f};
            c = __builtin_amdgcn_mfma_f32_16x16x32_f16(af[i][0], bf[j][0], c, 0, 0, 0);
            c = __builtin_amdgcn_mfma_f32_16x16x32_f16(af[i][1], bf[j][1], c, 0, 0, 0);
#pragma unroll
            for (int reg = 0; reg < 4; ++reg)
                out[(size_t)(m0 + i * 16 + quad * 4 + reg) * S_LEN + n0 + j * 16 + l16] =
                    f2h(c[reg]);
        }
}

// ---------------------------------------------------------------------------
// Barrier-free flash attention, split-K=2.
// Block 256 thr = 4 waves: wave = (kh = w>>1, qg = w&1). Wave owns q rows
// [qb*32 + qg*16, +16) and keys [kh*1024, kh*1024+1024), 8 k-tiles of 128.
// Q/K/V fragments straight from global ([n][k]-layouts -> 16B contiguous);
// only wave-private LDS (Sp slot, 4.25 KB) for the P C->A transpose.
// End: kh=1 dumps (m,l,acc) to its slot, one barrier, kh=0 flash-merges.
// mfma_f32_16x16x32_f16 layouts (dtype-indep, verified): A[m=l16][k=quad*8+j],
// B[k=quad*8+j][n=l16], C row=quad*4+reg col=l16.
// ---------------------------------------------------------------------------
__global__ __launch_bounds__(256, 4)
void attn_fused(const unsigned short* __restrict__ qu,
                const unsigned short* __restrict__ kdat,
                const unsigned short* __restrict__ vtg,
                const unsigned short* __restrict__ pp,
                float* __restrict__ ctx, int head_base)
{
    __shared__ unsigned short SpAll[4][2176];   // per-wave 16x136 halfs (4352 B)

    const int t = threadIdx.x;
    const int wave = t >> 6, lane = t & 63;
    const int quad = lane >> 4, l16 = lane & 15;
    const int qg = wave & 1, kh = wave >> 1;
    const int z = blockIdx.x >> 6, qb = blockIdx.x & 63;
    const int g = head_base + z;
    const int q0 = qb * 32 + qg * 16;           // wave's 16 q rows

    const unsigned short* QU = qu   + (size_t)g * HEAD_ELEMS;   // [s][d]
    const unsigned short* Kg = kdat + (size_t)g * HEAD_ELEMS;   // [s][d]
    const unsigned short* Vg = vtg  + (size_t)g * HEAD_ELEMS;   // [d][s]
    const unsigned short* Pg = pp   + (size_t)z * SS;           // fp16
    unsigned short* Sp = &SpAll[wave][0];

    // Q fragments (loop-invariant)
    const v8s aq0 = *(const v8s*)(QU + (size_t)(q0 + l16) * DHD + quad * 8);
    const v8s aq1 = *(const v8s*)(QU + (size_t)(q0 + l16) * DHD + 32 + quad * 8);

    float m_run[4], l_run[4];
    v4f accv[4];
#pragma unroll
    for (int r = 0; r < 4; ++r) {
        m_run[r] = -1e30f; l_run[r] = 0.f;
        accv[r] = (v4f){0.f, 0.f, 0.f, 0.f};
    }
    const float scale = 0.04419417382415922f;   // 1/sqrt(512)

    for (int kt = 0; kt < 8; ++kt) {
        const int k0 = kh * 1024 + kt * 128;

        // QK^T: S[16 q][128 k]
        v4f sacc[8];
#pragma unroll
        for (int nt = 0; nt < 8; ++nt) {
            v8s b0 = *(const v8s*)(Kg + (size_t)(k0 + nt * 16 + l16) * DHD + quad * 8);
            v8s b1 = *(const v8s*)(Kg + (size_t)(k0 + nt * 16 + l16) * DHD + 32 + quad * 8);
            v4f c = (v4f){0.f, 0.f, 0.f, 0.f};
            c = __builtin_amdgcn_mfma_f32_16x16x32_f16(aq0, b0, c, 0, 0, 0);
            c = __builtin_amdgcn_mfma_f32_16x16x32_f16(aq1, b1, c, 0, 0, 0);
            sacc[nt] = c;
        }

        // + rel-shifted fp16 Ppos gather (flat trick, validated r3-r5)
#pragma unroll
        for (int nt = 0; nt < 8; ++nt) {
            int k = k0 + nt * 16 + l16;
#pragma unroll
            for (int reg = 0; reg < 4; ++reg) {
                int q = q0 + quad * 4 + reg;
                int dq = k - q;
                size_t addr = (size_t)q * (S_LEN - 1) + (S_LEN - 1) + k - (dq >= 1 ? 1 : 0);
                float pv = h2f(Pg[addr]);
                sacc[nt][reg] += (dq == 1) ? 0.f : pv;
            }
        }

        // online softmax (row = quad*4+reg, 16 cols/lane-group x 8 nt)
#pragma unroll
        for (int reg = 0; reg < 4; ++reg) {
            float tm = -1e30f;
#pragma unroll
            for (int nt = 0; nt < 8; ++nt) {
                sacc[nt][reg] *= scale;
                tm = fmaxf(tm, sacc[nt][reg]);
            }
            tm = fmaxf(tm, __shfl_xor(tm, 1));
            tm = fmaxf(tm, __shfl_xor(tm, 2));
            tm = fmaxf(tm, __shfl_xor(tm, 4));
            tm = fmaxf(tm, __shfl_xor(tm, 8));
            float mn = fmaxf(m_run[reg], tm);
            float al = __expf(m_run[reg] - mn);
            float rs = 0.f;
#pragma unroll
            for (int nt = 0; nt < 8; ++nt) {
                sacc[nt][reg] = __expf(sacc[nt][reg] - mn);
                rs += sacc[nt][reg];
            }
            rs += __shfl_xor(rs, 1);
            rs += __shfl_xor(rs, 2);
            rs += __shfl_xor(rs, 4);
            rs += __shfl_xor(rs, 8);
            l_run[reg] = l_run[reg] * al + rs;
            m_run[reg] = mn;
#pragma unroll
            for (int ntd = 0; ntd < 4; ++ntd) accv[ntd][reg] *= al;
        }

        // P -> fp16 into wave-private Sp (C layout rows), then PV
#pragma unroll
        for (int nt = 0; nt < 8; ++nt)
#pragma unroll
            for (int reg = 0; reg < 4; ++reg)
                Sp[(quad * 4 + reg) * 136 + nt * 16 + l16] = f2h(sacc[nt][reg]);

#pragma unroll
        for (int c4 = 0; c4 < 4; ++c4) {
            v8s ap = *(const v8s*)&Sp[l16 * 136 + c4 * 32 + quad * 8];
#pragma unroll
            for (int ntd = 0; ntd < 4; ++ntd) {
                v8s bv8 = *(const v8s*)(Vg + (size_t)(ntd * 16 + l16) * S_LEN +
                                        k0 + c4 * 32 + quad * 8);
                accv[ntd] = __builtin_amdgcn_mfma_f32_16x16x32_f16(ap, bv8, accv[ntd], 0, 0, 0);
            }
        }
    }

    // split-K merge: kh=1 dumps raw state into its Sp slot (float view)
    if (kh == 1) {
        float* mb = (float*)&SpAll[wave][0];
#pragma unroll
        for (int ntd = 0; ntd < 4; ++ntd)
#pragma unroll
            for (int reg = 0; reg < 4; ++reg)
                mb[lane * 16 + ntd * 4 + reg] = accv[ntd][reg];
        if (l16 == 0) {
#pragma unroll
            for (int reg = 0; reg < 4; ++reg) {
                mb[1024 + (quad * 4 + reg) * 2]     = m_run[reg];
                mb[1024 + (quad * 4 + reg) * 2 + 1] = l_run[reg];
            }
        }
    }
    __syncthreads();
    if (kh == 0) {
        const float* mb = (const float*)&SpAll[2 + qg][0];
        const int bb = g >> 3, h = g & 7;
#pragma unroll
        for (int reg = 0; reg < 4; ++reg) {
            float m1 = mb[1024 + (quad * 4 + reg) * 2];
            float l1 = mb[1024 + (quad * 4 + reg) * 2 + 1];
            float mn = fmaxf(m_run[reg], m1);
            float a0 = __expf(m_run[reg] - mn);
            float a1 = __expf(m1 - mn);
            float inv = 1.f / (l_run[reg] * a0 + l1 * a1);
            int q = q0 + quad * 4 + reg;
#pragma unroll
            for (int ntd = 0; ntd < 4; ++ntd) {
                float o = (accv[ntd][reg] * a0 + mb[lane * 16 + ntd * 4 + reg] * a1) * inv;
                ctx[((size_t)(bb * S_LEN + q)) * DM + h * DHD + ntd * 16 + l16] = o;
            }
        }
    }
}

// ---------------------------------------------------------------------------
// Output GEMM: out[4096,512] = ctx @ Wo + bo (fp32)
// ---------------------------------------------------------------------------
__global__ __launch_bounds__(256)
void out_gemm(const float* __restrict__ ca,
              const float* __restrict__ Wo, const float* __restrict__ bo,
              float* __restrict__ out)
{
    __shared__ float Ast[32][132];
    __shared__ float Bs[32][132];
    const int t = threadIdx.x;
    const int tx = t & 15, ty = t >> 4;
    const int n0 = blockIdx.x * 128, m0 = blockIdx.y * 128;

    float acc[8][8];
#pragma unroll
    for (int i = 0; i < 8; ++i)
#pragma unroll
        for (int j = 0; j < 8; ++j) acc[i][j] = 0.f;

    for (int k0 = 0; k0 < 512; k0 += 32) {
#pragma unroll
        for (int i = 0; i < 4; ++i) {
            int f = t + i * 256;
            int row = f >> 3, kq = f & 7;
            float4 a4 = *(const float4*)(ca + (size_t)(m0 + row) * 512 + k0 + kq * 4);
            Ast[kq * 4 + 0][row] = a4.x; Ast[kq * 4 + 1][row] = a4.y;
            Ast[kq * 4 + 2][row] = a4.z; Ast[kq * 4 + 3][row] = a4.w;
        }
#pragma unroll
        for (int i = 0; i < 4; ++i) {
            int f = t + i * 256;
            int row = f >> 5, c4 = f & 31;
            *(float4*)&Bs[row][c4 * 4] =
                *(const float4*)(Wo + (size_t)(k0 + row) * 512 + n0 + c4 * 4);
        }
        __syncthreads();
#pragma unroll
        for (int kc = 0; kc < 32; ++kc) {
            float a[8], b[8];
            *(float4*)&a[0] = *(const float4*)&Ast[kc][ty * 8];
            *(float4*)&a[4] = *(const float4*)&Ast[kc][ty * 8 + 4];
            *(float4*)&b[0] = *(const float4*)&Bs[kc][tx * 8];
            *(float4*)&b[4] = *(const float4*)&Bs[kc][tx * 8 + 4];
#pragma unroll
            for (int i = 0; i < 8; ++i)
#pragma unroll
                for (int j = 0; j < 8; ++j) acc[i][j] = fmaf(a[i], b[j], acc[i][j]);
        }
        __syncthreads();
    }

#pragma unroll
    for (int i = 0; i < 8; ++i) {
        int gm = m0 + ty * 8 + i;
#pragma unroll
        for (int j4 = 0; j4 < 2; ++j4) {
            int gn = n0 + tx * 8 + j4 * 4;
            float4 bi = *(const float4*)(bo + gn);
            *(float4*)(out + (size_t)gm * 512 + gn) =
                make_float4(acc[i][j4 * 4 + 0] + bi.x, acc[i][j4 * 4 + 1] + bi.y,
                            acc[i][j4 * 4 + 2] + bi.z, acc[i][j4 * 4 + 3] + bi.w);
        }
    }
}

// Fallback when ws_size is insufficient: clean mismatch instead of OOB writes.
__global__ void zero_fill(float* __restrict__ p, int n)
{
    int i = blockIdx.x * 256 + threadIdx.x;
    if (i < n) p[i] = 0.f;
}

// ---------------------------------------------------------------------------
extern "C" void kernel_launch(void* const* d_in, const int* in_sizes, int n_in,
                              void* d_out, int out_size, void* d_ws, size_t ws_size,
                              hipStream_t stream)
{
    const float* x   = (const float*)d_in[0];
    const float* pos = (const float*)d_in[1];
    const float* Wq  = (const float*)d_in[2];
    const float* bq  = (const float*)d_in[3];
    const float* Wk  = (const float*)d_in[4];
    const float* bk  = (const float*)d_in[5];
    const float* Wv  = (const float*)d_in[6];
    const float* bv  = (const float*)d_in[7];
    const float* Wp  = (const float*)d_in[8];
    const float* u   = (const float*)d_in[9];
    const float* v   = (const float*)d_in[10];
    const float* Wo  = (const float*)d_in[11];
    const float* bo  = (const float*)d_in[12];
    char* wsb  = (char*)d_ws;
    float* out = (float*)d_out;

    // Workspace guard: need BY_PP + >=1 head of fp16 Ppos (37.7 MB min).
    if (ws_size < (size_t)BY_PP + PP_HEAD_BYTES) {
        zero_fill<<<(out_size + 255) / 256, 256, 0, stream>>>(out, out_size);
        return;
    }

    // 1. projections
    proj_kernel<<<dim3(4, 32, 4), 256, 0, stream>>>(x, pos, Wq, bq, Wk, bk, Wv, bv,
                                                    Wp, u, v, wsb);

    // 2. attention in head-chunks sized to workspace
    int c = (int)((ws_size - (size_t)BY_PP) / (size_t)PP_HEAD_BYTES);
    if (c < 1) c = 1;
    if (c > NBH) c = NBH;

    for (int g0 = 0; g0 < NBH; g0 += c) {
        int cc = (NBH - g0 < c) ? (NBH - g0) : c;
        pos_gemm<<<dim3(16, 16, cc), 256, 0, stream>>>(
            (const unsigned short*)(wsb + BY_QV),
            (const unsigned short*)(wsb + BY_PB),
            (unsigned short*)(wsb + BY_PP), g0);
        attn_fused<<<dim3(cc * 64), 256, 0, stream>>>(
            (const unsigned short*)(wsb + BY_QU),
            (const unsigned short*)(wsb + BY_K),
            (const unsigned short*)(wsb + BY_VT),
            (const unsigned short*)(wsb + BY_PP),
            (float*)(wsb + BY_CTX), g0);
    }

    // 3. output projection
    out_gemm<<<dim3(4, 32, 1), 256, 0, stream>>>((const float*)(wsb + BY_CTX),
                                                 Wo, bo, out);
}